// Round 9
// baseline (1117.343 us; speedup 1.0000x reference)
//
#include <hip/hip_runtime.h>
#include <stdint.h>

#define DEVI __device__ __forceinline__
#define FENCE() asm volatile("" ::: "memory")
#define BAR() do{ FENCE(); __builtin_amdgcn_s_barrier(); FENCE(); }while(0)

typedef short short8 __attribute__((ext_vector_type(8)));
typedef short short4v __attribute__((ext_vector_type(4)));
typedef float f32x4 __attribute__((ext_vector_type(4)));

DEVI float bf2f(unsigned short s){ union{unsigned u; float f;} x; x.u = ((unsigned)s)<<16; return x.f; }
DEVI unsigned short f2bf(float f){ union{float f; unsigned u;} x; x.f=f; unsigned r = x.u + 0x7fff + ((x.u>>16)&1); return (unsigned short)(r>>16); }

DEVI void gload_lds16(const void* g, void* l){
  __builtin_amdgcn_global_load_lds((const __attribute__((address_space(1))) unsigned int*)g,
                                   (__attribute__((address_space(3))) unsigned int*)l, 16, 0, 0);
}

// ---------------------------------------------------------------------------
// fp32 [K][N] (optionally batched z) -> bf16 [N][K]
__global__ __launch_bounds__(256)
void transpose_cvt(const float* __restrict__ in, unsigned short* __restrict__ out, int K, int N)
{
  __shared__ float tile[32][33];
  size_t zoff = (size_t)blockIdx.z * K * N;
  const float* src = in + zoff;
  unsigned short* dst = out + zoff;
  int kb = blockIdx.y*32, nb = blockIdx.x*32;
  int t = threadIdx.x;
  int tr = t>>3, tc = (t&7)*4;
  float4 v = *(const float4*)(src + (size_t)(kb+tr)*N + nb + tc);
  tile[tr][tc+0]=v.x; tile[tr][tc+1]=v.y; tile[tr][tc+2]=v.z; tile[tr][tc+3]=v.w;
  __syncthreads();
  short4v ov;
  ov[0] = (short)f2bf(tile[tc+0][tr]);
  ov[1] = (short)f2bf(tile[tc+1][tr]);
  ov[2] = (short)f2bf(tile[tc+2][tr]);
  ov[3] = (short)f2bf(tile[tc+3][tr]);
  *(short4v*)(dst + (size_t)(nb+tr)*K + kb + tc) = ov;
}

// ---------------------------------------------------------------------------
// w1 fp32 [2048][4096] -> permuted bf16 [4096][2048]: permuted row np holds
// source col c(np) = (np&16 ? 2048 : 0) + ((np>>5)<<4) + (np&15)
__global__ __launch_bounds__(256)
void transpose_cvt_w1(const float* __restrict__ w1, unsigned short* __restrict__ outp)
{
  __shared__ float tile[32][33];
  int e = blockIdx.z;
  const float* src = w1 + (size_t)e*2048*4096;
  unsigned short* dst = outp + (size_t)e*4096*2048;
  int np0 = blockIdx.x*32;
  int k0 = blockIdx.y*32;
  int g = np0 >> 5;
  int t = threadIdx.x;
  int tr = t>>3, tc = (t&7)*4;
  int srccol = (tc < 16) ? (g*16 + tc) : (2048 + g*16 + (tc-16));
  float4 v = *(const float4*)(src + (size_t)(k0+tr)*4096 + srccol);
  tile[tr][tc+0]=v.x; tile[tr][tc+1]=v.y; tile[tr][tc+2]=v.z; tile[tr][tc+3]=v.w;
  __syncthreads();
  short4v ov;
  ov[0] = (short)f2bf(tile[tc+0][tr]);
  ov[1] = (short)f2bf(tile[tc+1][tr]);
  ov[2] = (short)f2bf(tile[tc+2][tr]);
  ov[3] = (short)f2bf(tile[tc+3][tr]);
  *(short4v*)(dst + (size_t)(np0+tr)*2048 + k0 + tc) = ov;
}

// ---------------------------------------------------------------------------
__global__ __launch_bounds__(256)
void rmsnorm_k(const float* __restrict__ x, const float* __restrict__ gw,
               const float* __restrict__ bw, unsigned short* __restrict__ xn)
{
  int row = blockIdx.x*4 + (threadIdx.x>>6);
  int lane = threadIdx.x & 63;
  const float* xr = x + (size_t)row*512 + lane*8;
  float4 a = *(const float4*)xr;
  float4 c = *(const float4*)(xr+4);
  float ss = a.x*a.x+a.y*a.y+a.z*a.z+a.w*a.w + c.x*c.x+c.y*c.y+c.z*c.z+c.w*c.w;
  #pragma unroll
  for (int m=1;m<64;m<<=1) ss += __shfl_xor(ss, m);
  float inv = 1.0f / sqrtf(ss*(1.f/512.f) + 1e-6f);
  const float* gr = gw + lane*8; const float* br = bw + lane*8;
  float4 g0=*(const float4*)gr, g1=*(const float4*)(gr+4);
  float4 b0=*(const float4*)br, b1=*(const float4*)(br+4);
  short8 o;
  o[0]=(short)f2bf(a.x*inv*g0.x + b0.x);
  o[1]=(short)f2bf(a.y*inv*g0.y + b0.y);
  o[2]=(short)f2bf(a.z*inv*g0.z + b0.z);
  o[3]=(short)f2bf(a.w*inv*g0.w + b0.w);
  o[4]=(short)f2bf(c.x*inv*g1.x + b1.x);
  o[5]=(short)f2bf(c.y*inv*g1.y + b1.y);
  o[6]=(short)f2bf(c.z*inv*g1.z + b1.z);
  o[7]=(short)f2bf(c.w*inv*g1.w + b1.w);
  *(short8*)(xn + (size_t)row*512 + lane*8) = o;
}

// ---------------------------------------------------------------------------
// 256x256 pipelined GEMM, 4 phases/K-tile, deep A-prefetch:
//  - A triple-buffered (3 x 32KB), staged 2 K-tiles ahead (P0 of kt -> A[kt+2])
//  - B double-buffered (2 x 32KB), staged 2 K-tiles ahead (P1/P2 -> B[kt+2])
//  - counted vmcnt(8) at P3: the 8 newest outstanding loads are exactly
//    A[kt+2]+B[kt+2], so A[kt+1]/B[kt+1] are guaranteed landed (FIFO).
//  - LDS = 160 KiB total. XCD-chunked block swizzle (all grids % 8 == 0).
// Slot-reuse proof: A[kt+2] slot ((kt+2)%3) last read in P3 of kt-1 (drained
// at its LGKM0), staging issues at P0 of kt after that barrier. B[kt+2] slot
// ((kt+2)&1 = kt&1) fully read at P0 of kt (all B-frags), staged P1/P2.
// EPI: 0 = fp32 out + bias; 1 = bf16 out + bias; 2 = fused SwiGLU (permuted
//      W1, N=4096 acc -> 2048-col bf16 out; bias[0..2047]=a, [2048..]=gate)
#define READ_AFR(Q) do{ \
  _Pragma("unroll") \
  for (int m2=0;m2<2;m2++){ \
    int rt = wm*128 + ((Q)*2+m2)*16 + lrow; \
    _Pragma("unroll") \
    for (int kk=0;kk<2;kk++) \
      afr[m2][kk] = *(const short8*)(sA + rt*128 + (((lg+kk*4)^(rt&7))<<4)); \
  } \
}while(0)

#define QUADP(Q) do{ \
  __builtin_amdgcn_s_setprio(1); \
  _Pragma("unroll") \
  for (int m2=0;m2<2;m2++){ \
    _Pragma("unroll") \
    for (int n=0;n<4;n++){ \
      _Pragma("unroll") \
      for (int kk=0;kk<2;kk++) \
        acc[(Q)*2+m2][n] = __builtin_amdgcn_mfma_f32_16x16x32_bf16(afr[m2][kk], bfr[n][kk], acc[(Q)*2+m2][n], 0,0,0); \
    } \
  } \
  __builtin_amdgcn_s_setprio(0); \
}while(0)

#define LGKM0() do{ \
  asm volatile("s_waitcnt lgkmcnt(0)" ::: "memory"); \
  __builtin_amdgcn_sched_barrier(0); \
}while(0)

template<int EPI>
__global__ __launch_bounds__(512, 2)
void gemmT(const unsigned short* __restrict__ A, const unsigned short* __restrict__ B,
           const float* __restrict__ bias,
           float* __restrict__ Cf, unsigned short* __restrict__ Ch,
           int M, int N, int K,
           const int* __restrict__ off, long long strideBz, long long strideBiasz)
{
  __shared__ char smem[163840];   // A: 3 x 32KB @0; B: 2 x 32KB @98304
  // T1 XCD-chunked bijective swizzle (z slow -> one expert's tiles per chunk)
  int gx = gridDim.x, gy = gridDim.y;
  int pl = gx*gy;
  int lin = ((int)blockIdx.z*gy + (int)blockIdx.y)*gx + (int)blockIdx.x;
  int nwg = pl*(int)gridDim.z;
  int cpx = nwg >> 3;
  int swz = (lin & 7)*cpx + (lin >> 3);
  int z = swz / pl; int rxy = swz - z*pl;
  int by = rxy / gx; int bx = rxy - by*gx;

  int rowbase = 0, Mz = M;
  if (off){ rowbase = off[z]; Mz = off[z+1] - rowbase; }
  int row0 = by * 256;
  if (row0 >= Mz) return;
  int col0 = bx * 256;
  const unsigned short* Ab = A + (size_t)(rowbase + row0) * K;
  const unsigned short* Bb = B + (size_t)z * strideBz + (size_t)col0 * K;
  const float* biasz = bias + (size_t)z * strideBiasz;

  int tid = threadIdx.x;
  int lane = tid & 63, w = tid >> 6;
  int lrow = lane & 15, lg = lane >> 4;
  int wm = w >> 2, wn = w & 3;

  f32x4 acc[8][4];
  #pragma unroll
  for (int i=0;i<8;i++){
    #pragma unroll
    for (int j=0;j<4;j++) acc[i][j] = f32x4{0.f,0.f,0.f,0.f};
  }
  int nkt = K >> 6;
  // H0/H1 = A rows 0-127 / 128-255 (slot kt%3); H2/H3 = B rows 0-127 / 128-255
  auto stage = [&](int kt2, int H){
    if (kt2 >= nkt) return;
    char* sl;
    if (H < 2) sl = smem + (kt2 % 3) * 32768 + H * 16384;
    else       sl = smem + 98304 + (kt2 & 1) * 32768 + (H - 2) * 16384;
    int k0 = kt2 << 6;
    const unsigned short* src = (H < 2) ? Ab : Bb;
    int rbase = (H & 1) * 128;
    #pragma unroll
    for (int i=0;i<2;i++){
      int si = i*512 + tid;
      int r = si >> 3, kb = (si & 7) ^ (r & 7);
      gload_lds16(src + (size_t)(rbase + r)*K + k0 + kb*8, sl + si*16);
    }
  };
  // prologue: A[0],B[0],A[1],B[1] (16 loads); wait kt0 (leave kt1's 8 in flight)
  stage(0,0); stage(0,1); stage(0,2); stage(0,3);
  stage(1,0); stage(1,1); stage(1,2); stage(1,3);
  asm volatile("s_waitcnt vmcnt(8)" ::: "memory");
  BAR();
  for (int kt = 0; kt < nkt; kt++){
    char* sA = smem + (kt % 3) * 32768;
    char* sB = smem + 98304 + (kt & 1) * 32768;
    short8 bfr[4][2], afr[2][2];
    // ---- P0: all B-frags + A quad0; stage A[kt+2] (both halves)
    #pragma unroll
    for (int n=0;n<4;n++){
      int ct = wn*64 + n*16 + lrow;
      #pragma unroll
      for (int kk=0;kk<2;kk++)
        bfr[n][kk] = *(const short8*)(sB + ct*128 + (((lg+kk*4)^(ct&7))<<4));
    }
    READ_AFR(0);
    stage(kt+2, 0); stage(kt+2, 1);
    BAR();
    LGKM0();
    QUADP(0);
    BAR();
    // ---- P1: A quad1; stage B[kt+2]-lo
    READ_AFR(1);
    stage(kt+2, 2);
    BAR();
    LGKM0();
    QUADP(1);
    BAR();
    // ---- P2: A quad2; stage B[kt+2]-hi
    READ_AFR(2);
    stage(kt+2, 3);
    BAR();
    LGKM0();
    QUADP(2);
    BAR();
    // ---- P3: A quad3; counted vmcnt(8) -> A[kt+1],B[kt+1] landed
    READ_AFR(3);
    if (kt + 2 < nkt) { asm volatile("s_waitcnt vmcnt(8)" ::: "memory"); }
    else              { asm volatile("s_waitcnt vmcnt(0)" ::: "memory"); }
    BAR();
    LGKM0();
    QUADP(3);
    BAR();
  }
  #pragma unroll
  for (int m=0;m<8;m++){
    #pragma unroll
    for (int j=0;j<4;j++){
      int row = row0 + wm*128 + m*16 + lg*4 + j;
      if (row < Mz){
        size_t rg = (size_t)(rowbase + row);
        if constexpr (EPI == 2){
          #pragma unroll
          for (int nf=0;nf<4;nf+=2){
            int pcol = col0 + wn*64 + nf*16;
            int scol = ((pcol>>5)<<4) + lrow;
            float av = acc[m][nf][j]   + biasz[scol];
            float gv = acc[m][nf+1][j] + biasz[2048 + scol];
            float sg = gv / (1.f + __expf(-gv));
            Ch[rg*2048 + scol] = f2bf(av * sg);
          }
        } else {
          #pragma unroll
          for (int n=0;n<4;n++){
            int col = col0 + wn*64 + n*16 + lrow;
            float v = acc[m][n][j] + biasz[col];
            size_t idx = rg * N + col;
            if constexpr (EPI == 0) Cf[idx] = v;
            else                    Ch[idx] = f2bf(v);
          }
        }
      }
    }
  }
}

// ---------------------------------------------------------------------------
// Legacy 128x128 GEMM for the small proj matmul: +resid, fp32+bf16 out
__global__ __launch_bounds__(256)
void gemm_proj(const unsigned short* __restrict__ A, const unsigned short* __restrict__ B,
               const float* __restrict__ bias,
               float* __restrict__ Cf, unsigned short* __restrict__ Ch,
               const float* __restrict__ resid, int M, int N, int K)
{
  __shared__ char smem[32768];
  char* smA = smem; char* smB = smem + 16384;
  int row0 = blockIdx.y * 128;
  int col0 = blockIdx.x * 128;
  int t = threadIdx.x, w = t>>6, lane = t&63;
  int lrow = lane&15, lg = lane>>4;
  int wr = w>>1, wc = w&1;

  f32x4 acc[4][4];
  #pragma unroll
  for (int i=0;i<4;i++){
    #pragma unroll
    for (int j=0;j<4;j++) acc[i][j] = f32x4{0.f,0.f,0.f,0.f};
  }
  const size_t Abase = (size_t)row0 * K;
  const size_t Bbase = (size_t)col0 * K;
  int nkt = K >> 6;
  for (int kt=0; kt<nkt; kt++){
    __syncthreads();
    int k0 = kt*64;
    #pragma unroll
    for (int i=0;i<4;i++){
      int s = (i*4 + w)*64 + lane;
      int r = s>>3;
      int kb = (s&7) ^ (r&7);
      gload_lds16(A + Abase + (size_t)r*K + k0 + kb*8, smA + (size_t)(i*4+w)*1024);
      gload_lds16(B + Bbase + (size_t)r*K + k0 + kb*8, smB + (size_t)(i*4+w)*1024);
    }
    __syncthreads();
    #pragma unroll
    for (int ks=0; ks<2; ks++){
      short8 af[4], bf[4];
      int kbb = lg + ks*4;
      #pragma unroll
      for (int m=0;m<4;m++){
        int rt = wr*64 + m*16 + lrow;
        af[m] = *(const short8*)(smA + rt*128 + ((kbb ^ (rt&7))<<4));
      }
      #pragma unroll
      for (int n=0;n<4;n++){
        int rt = wc*64 + n*16 + lrow;
        bf[n] = *(const short8*)(smB + rt*128 + ((kbb ^ (rt&7))<<4));
      }
      #pragma unroll
      for (int m=0;m<4;m++){
        #pragma unroll
        for (int n=0;n<4;n++)
          acc[m][n] = __builtin_amdgcn_mfma_f32_16x16x32_bf16(af[m], bf[n], acc[m][n], 0,0,0);
      }
    }
  }
  #pragma unroll
  for (int m=0;m<4;m++){
    int rloc = wr*64 + m*16 + lg*4;
    #pragma unroll
    for (int j=0;j<4;j++){
      int row = row0 + rloc + j;
      size_t rg = (size_t)row;
      #pragma unroll
      for (int n=0;n<4;n++){
        int col = col0 + wc*64 + n*16 + lrow;
        float v = acc[m][n][j] + bias[col];
        size_t idx = rg * N + col;
        v += resid[idx];
        Cf[idx] = v;
        Ch[idx] = f2bf(v);
      }
    }
  }
}

// ---------------------------------------------------------------------------
__global__ __launch_bounds__(256)
void prep_qkv(const float* __restrict__ qkv, const float* __restrict__ alpha,
              unsigned short* __restrict__ q_s, unsigned short* __restrict__ k_hat,
              unsigned short* __restrict__ v_t)
{
  int idx = blockIdx.x*4 + (threadIdx.x>>6);
  int lane = threadIdx.x & 63;
  int h = idx & 7, bt = idx >> 3;
  size_t base = (size_t)bt*1536 + h*64 + lane;
  float qv = qkv[base], kv = qkv[base+512], vv = qkv[base+1024];
  float qs2 = qv*qv, ks2 = kv*kv;
  #pragma unroll
  for (int m=1;m<64;m<<=1){ qs2 += __shfl_xor(qs2, m); ks2 += __shfl_xor(ks2, m); }
  float qh = qv / (sqrtf(qs2) + 1e-5f) * alpha[h];
  float kh = kv / (sqrtf(ks2) + 1e-5f);
  int b = bt >> 10, tt = bt & 1023;
  size_t hb = ((size_t)(b*8+h))*1024*64;
  q_s[hb + (size_t)tt*64 + lane] = f2bf(qh);
  k_hat[hb + (size_t)tt*64 + lane] = f2bf(kh);
  v_t[((size_t)(b*8+h)*64 + lane)*1024 + tt] = f2bf(vv);
}

// ---------------------------------------------------------------------------
// Flash attention, 64-row q-tiles (grid 16x16 = 256 blocks).
__global__ __launch_bounds__(256)
void attn_k(const unsigned short* __restrict__ q_s, const unsigned short* __restrict__ k_hat,
            const unsigned short* __restrict__ v_t, unsigned short* __restrict__ y)
{
  __shared__ char sm[51200];
  char* smK = sm + 18432;
  char* smV = sm + 34816;
  int qt = blockIdx.x, bh = blockIdx.y;
  int b = bh>>3, h = bh&7;
  int t = threadIdx.x, w = t>>6, lane = t&63;
  int lrow = lane&15, lg = lane>>4;
  int q0 = qt*64;
  const size_t hQK = (size_t)bh*1024*64;
  const size_t hV  = (size_t)bh*64*1024;

  #pragma unroll
  for (int i=0;i<2;i++){
    int si = i*256 + t;
    int r = si>>3, kb = (si&7)^(r&7);
    gload_lds16(q_s + hQK + (size_t)(q0+r)*64 + kb*8, sm + (size_t)si*16);
  }
  __syncthreads();
  short8 qf[2];
  #pragma unroll
  for (int ks=0;ks<2;ks++){
    int rt = w*16 + lrow;
    int kbb = lg + ks*4;
    qf[ks] = *(const short8*)(sm + rt*128 + ((kbb^(rt&7))<<4));
  }
  f32x4 oacc[4];
  #pragma unroll
  for (int j=0;j<4;j++) oacc[j] = f32x4{0.f,0.f,0.f,0.f};
  float mrun[4], lrun[4];
  #pragma unroll
  for (int j=0;j<4;j++){ mrun[j] = -1e30f; lrun[j] = 0.f; }
  char* Pw = sm + w*2304;

  int ktmax = (q0 + 63) >> 7;
  for (int kt=0; kt<=ktmax; kt++){
    __syncthreads();
    int t0 = kt*128;
    #pragma unroll
    for (int i=0;i<4;i++){
      int s = (i*4+w)*64 + lane;
      int r = s>>3, kb = (s&7)^(r&7);
      gload_lds16(k_hat + hQK + (size_t)(t0+r)*64 + kb*8, smK + (size_t)(i*4+w)*1024);
    }
    #pragma unroll
    for (int i=0;i<4;i++){
      int s = (i*4+w)*64 + lane;
      int d = s>>4, kb2 = s&15;
      int kb = kb2 ^ (d&7);
      gload_lds16(v_t + hV + (size_t)d*1024 + t0 + kb*8, smV + (size_t)(i*4+w)*1024);
    }
    __syncthreads();

    f32x4 sacc[8];
    #pragma unroll
    for (int j=0;j<8;j++) sacc[j] = f32x4{0.f,0.f,0.f,0.f};
    #pragma unroll
    for (int ks=0;ks<2;ks++){
      short8 kf[8];
      int kbb = lg + ks*4;
      #pragma unroll
      for (int nf=0;nf<8;nf++){
        int rt = nf*16+lrow;
        kf[nf] = *(const short8*)(smK + rt*128 + ((kbb^(rt&7))<<4));
      }
      #pragma unroll
      for (int nf=0;nf<8;nf++)
        sacc[nf] = __builtin_amdgcn_mfma_f32_16x16x32_bf16(qf[ks], kf[nf], sacc[nf], 0,0,0);
    }
    if (kt == ktmax){
      #pragma unroll
      for (int nf=0;nf<8;nf++){
        #pragma unroll
        for (int j=0;j<4;j++){
          int qi = q0 + w*16 + lg*4 + j;
          int ki = t0 + nf*16 + lrow;
          if (ki > qi) sacc[nf][j] = -1e30f;
        }
      }
    }
    #pragma unroll
    for (int j=0;j<4;j++){
      float mx = sacc[0][j];
      #pragma unroll
      for (int nf=1;nf<8;nf++) mx = fmaxf(mx, sacc[nf][j]);
      #pragma unroll
      for (int m=1;m<16;m<<=1) mx = fmaxf(mx, __shfl_xor(mx, m));
      float mnew = fmaxf(mrun[j], mx);
      float sc = __expf(mrun[j] - mnew);
      float rs = 0.f;
      #pragma unroll
      for (int nf=0;nf<8;nf++){
        float p = __expf(sacc[nf][j] - mnew);
        sacc[nf][j] = p; rs += p;
      }
      #pragma unroll
      for (int m=1;m<16;m<<=1) rs += __shfl_xor(rs, m);
      lrun[j] = lrun[j]*sc + rs;
      mrun[j] = mnew;
      #pragma unroll
      for (int n2=0;n2<4;n2++) oacc[n2][j] *= sc;
    }
    #pragma unroll
    for (int half=0; half<2; half++){
      #pragma unroll
      for (int nfh=0;nfh<4;nfh++){
        int nf = half*4 + nfh;
        #pragma unroll
        for (int j=0;j<4;j++){
          int row = lg*4 + j;
          int col = nfh*16 + lrow;
          *(unsigned short*)(Pw + (row*72 + col)*2) = f2bf(sacc[nf][j]);
        }
      }
      #pragma unroll
      for (int k2=0;k2<2;k2++){
        int ks2 = half*2 + k2;
        short8 pf, vf[4];
        pf = *(const short8*)(Pw + lrow*144 + lg*16 + k2*64);
        #pragma unroll
        for (int n2=0;n2<4;n2++){
          int d = n2*16+lrow;
          int kbb2 = lg + ks2*4;
          vf[n2] = *(const short8*)(smV + d*256 + ((kbb2^(d&7))<<4));
        }
        #pragma unroll
        for (int n2=0;n2<4;n2++)
          oacc[n2] = __builtin_amdgcn_mfma_f32_16x16x32_bf16(pf, vf[n2], oacc[n2], 0,0,0);
      }
    }
  }
  #pragma unroll
  for (int n2=0;n2<4;n2++){
    #pragma unroll
    for (int j=0;j<4;j++){
      float v = oacc[n2][j] / lrun[j];
      int qi = q0 + w*16 + lg*4 + j;
      int d = n2*16 + lrow;
      y[((size_t)(b*1024+qi))*512 + h*64 + d] = f2bf(v);
    }
  }
}

// ---------------------------------------------------------------------------
__global__ __launch_bounds__(256)
void router_topk(const float* __restrict__ x2f, const float* __restrict__ rw,
                 const float* __restrict__ rb, float* __restrict__ gates)
{
  int tkn = blockIdx.x*4 + (threadIdx.x>>6);
  int lane = threadIdx.x & 63;
  int e = lane & 15, p = lane >> 4;
  const float* xr = x2f + (size_t)tkn*512;
  float part = 0.f;
  for (int d = p*128; d < p*128+128; d++)
    part += xr[d] * rw[d*16 + e];
  part += __shfl_xor(part, 16);
  part += __shfl_xor(part, 32);
  float logit = part + rb[e];
  float mx = logit;
  #pragma unroll
  for (int m=1;m<16;m<<=1) mx = fmaxf(mx, __shfl_xor(mx, m));
  float ex = __expf(logit - mx);
  float sm = ex;
  #pragma unroll
  for (int m=1;m<16;m<<=1) sm += __shfl_xor(sm, m);
  float prob = ex / sm;
  bool taken = false;
  float ssum = 0.f;
  #pragma unroll
  for (int r=0;r<8;r++){
    float cv = taken ? -1.f : prob;
    int ci = e;
    #pragma unroll
    for (int m=1;m<16;m<<=1){
      float ov = __shfl_xor(cv, m);
      int oi = __shfl_xor(ci, m);
      if (ov > cv || (ov == cv && oi < ci)){ cv = ov; ci = oi; }
    }
    if (e == ci) taken = true;
    ssum += cv;
  }
  if (lane < 16)
    gates[(size_t)tkn*16 + e] = taken ? prob / ssum : 0.f;
}

// ---------------------------------------------------------------------------
__global__ void listbuild(const float* __restrict__ gates, int* __restrict__ list,
                          int* __restrict__ slot, int* __restrict__ cnt)
{
  int e = blockIdx.x;
  int tid = threadIdx.x, w = tid>>6, lane = tid&63;
  __shared__ int sbase;
  __shared__ int wsum[4];
  if (tid==0) sbase = 0;
  __syncthreads();
  for (int c=0;c<8;c++){
    int tk = c*256 + tid;
    bool flag = gates[(size_t)tk*16 + e] > 0.f;
    unsigned long long bal = __ballot(flag);
    if (lane==0) wsum[w] = (int)__popcll(bal);
    __syncthreads();
    int wpref = 0;
    for (int i=0;i<w;i++) wpref += wsum[i];
    int tot = wsum[0]+wsum[1]+wsum[2]+wsum[3];
    int lpref = (int)__popcll(bal & ((1ull<<lane)-1ull));
    if (flag){
      int pos = sbase + wpref + lpref;
      list[e*2048 + pos] = tk;
      slot[(size_t)tk*16 + e] = pos;
    }
    __syncthreads();
    if (tid==0) sbase += tot;
    __syncthreads();
  }
  if (tid==0) cnt[e] = sbase;
}

__global__ void prefix_off(const int* __restrict__ cnt, int* __restrict__ off){
  if (threadIdx.x==0 && blockIdx.x==0){
    int a=0;
    for (int e=0;e<16;e++){ off[e]=a; a+=cnt[e]; }
    off[16]=a;
  }
}

__global__ __launch_bounds__(256)
void gather_rows(const unsigned short* __restrict__ x2h, const int* __restrict__ list,
                 const int* __restrict__ cnt, const int* __restrict__ off,
                 unsigned short* __restrict__ xe)
{
  int e = blockIdx.y;
  int s = blockIdx.x*4 + (threadIdx.x>>6);
  if (s >= cnt[e]) return;
  int lane = threadIdx.x & 63;
  int tk = list[e*2048 + s];
  *(short8*)(xe + ((size_t)(off[e]+s))*512 + lane*8) =
      *(const short8*)(x2h + (size_t)tk*512 + lane*8);
}

__global__ __launch_bounds__(256)
void combine_k(const float* __restrict__ x2f, const unsigned short* __restrict__ eo,
               const float* __restrict__ gates, const int* __restrict__ slot,
               const int* __restrict__ off, float* __restrict__ out)
{
  int tkn = blockIdx.x;
  __shared__ float gs[16];
  __shared__ int rws[16];
  int tid = threadIdx.x;
  if (tid < 16){
    float g = gates[(size_t)tkn*16 + tid];
    gs[tid] = g;
    rws[tid] = (g > 0.f) ? (off[tid] + slot[(size_t)tkn*16 + tid]) : 0;
  }
  __syncthreads();
  for (int d = tid; d < 512; d += 256){
    float v = x2f[(size_t)tkn*512 + d];
    #pragma unroll
    for (int e=0;e<16;e++){
      float g = gs[e];
      if (g > 0.f) v += g * bf2f(eo[(size_t)rws[e]*512 + d]);
    }
    out[(size_t)tkn*512 + d] = v;
  }
}

// ---------------------------------------------------------------------------
extern "C" void kernel_launch(void* const* d_in, const int* in_sizes, int n_in,
                              void* d_out, int out_size, void* d_ws, size_t ws_size,
                              hipStream_t stream) {
  (void)in_sizes; (void)n_in; (void)out_size; (void)ws_size;
  const float* x    = (const float*)d_in[0];
  const float* gw   = (const float*)d_in[1];
  const float* bw   = (const float*)d_in[2];
  const float* caw  = (const float*)d_in[3];
  const float* cab  = (const float*)d_in[4];
  const float* alpha= (const float*)d_in[5];
  const float* cpw  = (const float*)d_in[6];
  const float* cpb  = (const float*)d_in[7];
  const float* rw   = (const float*)d_in[8];
  const float* rb   = (const float*)d_in[9];
  const float* w_in = (const float*)d_in[10];
  const float* b_in = (const float*)d_in[11];
  const float* w1   = (const float*)d_in[12];
  const float* b1   = (const float*)d_in[13];
  const float* w2   = (const float*)d_in[14];
  const float* b2   = (const float*)d_in[15];
  const float* w_out= (const float*)d_in[16];
  const float* b_out= (const float*)d_in[17];

  char* ws = (char*)d_ws;
  size_t o = 0;
  auto alloc = [&](size_t bytes)->char*{
    char* p = ws + o;
    o += (bytes + 255) & ~(size_t)255;
    return p;
  };
  const size_t PADROWS = 16896;  // 16384 + 256-tile overread pad
  unsigned short* wT_attn = (unsigned short*)alloc(1536ull*512*2);
  unsigned short* wT_proj = (unsigned short*)alloc(512ull*512*2);
  unsigned short* wT_in   = (unsigned short*)alloc(16ull*2048*512*2);
  unsigned short* wT1p    = (unsigned short*)alloc(16ull*4096*2048*2);
  unsigned short* wT_2    = (unsigned short*)alloc(16ull*2048*2048*2);
  unsigned short* wT_out  = (unsigned short*)alloc(16ull*512*2048*2);
  unsigned short* xn      = (unsigned short*)alloc(2048ull*512*2);
  float*          qkv     = (float*)alloc(2048ull*1536*4);
  unsigned short* q_s     = (unsigned short*)alloc(2048ull*512*2);
  unsigned short* k_hat   = (unsigned short*)alloc(2048ull*512*2);
  unsigned short* v_t     = (unsigned short*)alloc(2048ull*512*2);
  unsigned short* ybuf    = (unsigned short*)alloc(2048ull*512*2);
  float*          x2f     = (float*)alloc(2048ull*512*4);
  unsigned short* x2h     = (unsigned short*)alloc(2048ull*512*2);
  float*          gates   = (float*)alloc(2048ull*16*4);
  int*            slot    = (int*)alloc(2048ull*16*4);
  int*            list    = (int*)alloc(16ull*2048*4);
  int*            cnt     = (int*)alloc(64);
  int*            off     = (int*)alloc(256);
  unsigned short* xe      = (unsigned short*)alloc(PADROWS*512*2);   // + eo alias
  unsigned short* hbuf    = (unsigned short*)alloc(PADROWS*2048*2);  // + o alias
  unsigned short* sbuf    = (unsigned short*)alloc(PADROWS*2048*2);
  unsigned short* eobuf   = xe;   // xe dead after h-GEMM
  unsigned short* obuf    = hbuf; // hbuf dead after fused SwiGLU GEMM

  dim3 blk(256);
  dim3 blk5(512);
  // weight transposes fp32 -> bf16 [N][K] (w1 -> permuted for fused SwiGLU)
  transpose_cvt<<<dim3(1536/32, 512/32, 1), blk, 0, stream>>>(caw, wT_attn, 512, 1536);
  transpose_cvt<<<dim3(512/32, 512/32, 1), blk, 0, stream>>>(cpw, wT_proj, 512, 512);
  transpose_cvt<<<dim3(2048/32, 512/32, 16), blk, 0, stream>>>(w_in, wT_in, 512, 2048);
  transpose_cvt_w1<<<dim3(4096/32, 2048/32, 16), blk, 0, stream>>>(w1, wT1p);
  transpose_cvt<<<dim3(2048/32, 2048/32, 16), blk, 0, stream>>>(w2, wT_2, 2048, 2048);
  transpose_cvt<<<dim3(512/32, 2048/32, 16), blk, 0, stream>>>(w_out, wT_out, 2048, 512);

  rmsnorm_k<<<512, blk, 0, stream>>>(x, gw, bw, xn);
  gemmT<0><<<dim3(6, 8, 1), blk5, 0, stream>>>(xn, wT_attn, cab, qkv, nullptr,
                                               2048, 1536, 512, nullptr, 0, 0);
  prep_qkv<<<4096, blk, 0, stream>>>(qkv, alpha, q_s, k_hat, v_t);
  attn_k<<<dim3(16,16), blk, 0, stream>>>(q_s, k_hat, v_t, ybuf);
  gemm_proj<<<dim3(4,16,1), blk, 0, stream>>>(ybuf, wT_proj, cpb, x2f, x2h, x, 2048, 512, 512);
  router_topk<<<512, blk, 0, stream>>>(x2f, rw, rb, gates);
  listbuild<<<16, blk, 0, stream>>>(gates, list, slot, cnt);
  prefix_off<<<1, 64, 0, stream>>>(cnt, off);
  gather_rows<<<dim3(512,16), blk, 0, stream>>>(x2h, list, cnt, off, xe);

  // experts (batched over z = expert, rows compacted via off[])
  gemmT<1><<<dim3(8,8,16), blk5, 0, stream>>>(xe, wT_in, b_in, nullptr, hbuf,
                                              0, 2048, 512, off, 2048ll*512, 2048);
  gemmT<2><<<dim3(16,8,16), blk5, 0, stream>>>(hbuf, wT1p, b1, nullptr, sbuf,
                                               0, 4096, 2048, off, 4096ll*2048, 4096);
  gemmT<1><<<dim3(8,8,16), blk5, 0, stream>>>(sbuf, wT_2, b2, nullptr, obuf,
                                              0, 2048, 2048, off, 2048ll*2048, 2048);
  gemmT<1><<<dim3(2,8,16), blk5, 0, stream>>>(obuf, wT_out, b_out, nullptr, eobuf,
                                              0, 512, 2048, off, 512ll*2048, 512);
  combine_k<<<2048, blk, 0, stream>>>(x2f, eobuf, gates, slot, off, (float*)d_out);
}

// Round 10
// 1105.013 us; speedup vs baseline: 1.0112x; 1.0112x over previous
//
#include <hip/hip_runtime.h>
#include <stdint.h>

#define DEVI __device__ __forceinline__
#define FENCE() asm volatile("" ::: "memory")
#define BAR() do{ FENCE(); __builtin_amdgcn_s_barrier(); FENCE(); }while(0)

typedef short short8 __attribute__((ext_vector_type(8)));
typedef short short4v __attribute__((ext_vector_type(4)));
typedef float f32x4 __attribute__((ext_vector_type(4)));

DEVI float bf2f(unsigned short s){ union{unsigned u; float f;} x; x.u = ((unsigned)s)<<16; return x.f; }
DEVI unsigned short f2bf(float f){ union{float f; unsigned u;} x; x.f=f; unsigned r = x.u + 0x7fff + ((x.u>>16)&1); return (unsigned short)(r>>16); }

DEVI void gload_lds16(const void* g, void* l){
  __builtin_amdgcn_global_load_lds((const __attribute__((address_space(1))) unsigned int*)g,
                                   (__attribute__((address_space(3))) unsigned int*)l, 16, 0, 0);
}

// ---------------------------------------------------------------------------
// fp32 [K][N] (optionally batched z) -> bf16 [N][K]
__global__ __launch_bounds__(256)
void transpose_cvt(const float* __restrict__ in, unsigned short* __restrict__ out, int K, int N)
{
  __shared__ float tile[32][33];
  size_t zoff = (size_t)blockIdx.z * K * N;
  const float* src = in + zoff;
  unsigned short* dst = out + zoff;
  int kb = blockIdx.y*32, nb = blockIdx.x*32;
  int t = threadIdx.x;
  int tr = t>>3, tc = (t&7)*4;
  float4 v = *(const float4*)(src + (size_t)(kb+tr)*N + nb + tc);
  tile[tr][tc+0]=v.x; tile[tr][tc+1]=v.y; tile[tr][tc+2]=v.z; tile[tr][tc+3]=v.w;
  __syncthreads();
  short4v ov;
  ov[0] = (short)f2bf(tile[tc+0][tr]);
  ov[1] = (short)f2bf(tile[tc+1][tr]);
  ov[2] = (short)f2bf(tile[tc+2][tr]);
  ov[3] = (short)f2bf(tile[tc+3][tr]);
  *(short4v*)(dst + (size_t)(nb+tr)*K + kb + tc) = ov;
}

// ---------------------------------------------------------------------------
// w1 fp32 [2048][4096] -> permuted bf16 [4096][2048]: permuted row np holds
// source col c(np) = (np&16 ? 2048 : 0) + ((np>>5)<<4) + (np&15)
__global__ __launch_bounds__(256)
void transpose_cvt_w1(const float* __restrict__ w1, unsigned short* __restrict__ outp)
{
  __shared__ float tile[32][33];
  int e = blockIdx.z;
  const float* src = w1 + (size_t)e*2048*4096;
  unsigned short* dst = outp + (size_t)e*4096*2048;
  int np0 = blockIdx.x*32;
  int k0 = blockIdx.y*32;
  int g = np0 >> 5;
  int t = threadIdx.x;
  int tr = t>>3, tc = (t&7)*4;
  int srccol = (tc < 16) ? (g*16 + tc) : (2048 + g*16 + (tc-16));
  float4 v = *(const float4*)(src + (size_t)(k0+tr)*4096 + srccol);
  tile[tr][tc+0]=v.x; tile[tr][tc+1]=v.y; tile[tr][tc+2]=v.z; tile[tr][tc+3]=v.w;
  __syncthreads();
  short4v ov;
  ov[0] = (short)f2bf(tile[tc+0][tr]);
  ov[1] = (short)f2bf(tile[tc+1][tr]);
  ov[2] = (short)f2bf(tile[tc+2][tr]);
  ov[3] = (short)f2bf(tile[tc+3][tr]);
  *(short4v*)(dst + (size_t)(np0+tr)*2048 + k0 + tc) = ov;
}

// ---------------------------------------------------------------------------
__global__ __launch_bounds__(256)
void rmsnorm_k(const float* __restrict__ x, const float* __restrict__ gw,
               const float* __restrict__ bw, unsigned short* __restrict__ xn)
{
  int row = blockIdx.x*4 + (threadIdx.x>>6);
  int lane = threadIdx.x & 63;
  const float* xr = x + (size_t)row*512 + lane*8;
  float4 a = *(const float4*)xr;
  float4 c = *(const float4*)(xr+4);
  float ss = a.x*a.x+a.y*a.y+a.z*a.z+a.w*a.w + c.x*c.x+c.y*c.y+c.z*c.z+c.w*c.w;
  #pragma unroll
  for (int m=1;m<64;m<<=1) ss += __shfl_xor(ss, m);
  float inv = 1.0f / sqrtf(ss*(1.f/512.f) + 1e-6f);
  const float* gr = gw + lane*8; const float* br = bw + lane*8;
  float4 g0=*(const float4*)gr, g1=*(const float4*)(gr+4);
  float4 b0=*(const float4*)br, b1=*(const float4*)(br+4);
  short8 o;
  o[0]=(short)f2bf(a.x*inv*g0.x + b0.x);
  o[1]=(short)f2bf(a.y*inv*g0.y + b0.y);
  o[2]=(short)f2bf(a.z*inv*g0.z + b0.z);
  o[3]=(short)f2bf(a.w*inv*g0.w + b0.w);
  o[4]=(short)f2bf(c.x*inv*g1.x + b1.x);
  o[5]=(short)f2bf(c.y*inv*g1.y + b1.y);
  o[6]=(short)f2bf(c.z*inv*g1.z + b1.z);
  o[7]=(short)f2bf(c.w*inv*g1.w + b1.w);
  *(short8*)(xn + (size_t)row*512 + lane*8) = o;
}

// ---------------------------------------------------------------------------
// 256x256 pipelined GEMM, 4 phases/K-tile (round-8 structure, compiler-
// scheduled waits): 512 thr / 8 waves (2Mx4N), per-wave 128x64 out, BK=64,
// 2 LDS K-tile slots (128 KiB). Per phase: {1 A-quadrant ds_read (+all B in
// P0) || stage -> bar -> setprio 16xMFMA -> bar}. NO explicit lgkmcnt/
// sched_barrier: frag reads are plain C++ loads, compiler emits fine-grained
// lgkmcnt before each MFMA use (all bfr used by every quad -> B-reads drained
// before P0's MFMA, i.e. before the stage into this slot's B at P1/P2; afr[Q]
// drained before QUADP(Q), before the closing barrier). vmcnt(4) at P3 FIFO:
// leaves only B[kt+2]'s 4 loads in flight; A[kt+1]/B[kt+1] landed.
// EPI: 0 = fp32 out + bias; 1 = bf16 out + bias; 2 = fused SwiGLU (permuted
//      W1, N=4096 acc -> 2048-col bf16 out; bias[0..2047]=a, [2048..]=gate)
#define READ_AFR(Q) do{ \
  _Pragma("unroll") \
  for (int m2=0;m2<2;m2++){ \
    int rt = wm*128 + ((Q)*2+m2)*16 + lrow; \
    _Pragma("unroll") \
    for (int kk=0;kk<2;kk++) \
      afr[m2][kk] = *(const short8*)(sA + rt*128 + (((lg+kk*4)^(rt&7))<<4)); \
  } \
}while(0)

#define QUADP(Q) do{ \
  __builtin_amdgcn_s_setprio(1); \
  _Pragma("unroll") \
  for (int m2=0;m2<2;m2++){ \
    _Pragma("unroll") \
    for (int n=0;n<4;n++){ \
      _Pragma("unroll") \
      for (int kk=0;kk<2;kk++) \
        acc[(Q)*2+m2][n] = __builtin_amdgcn_mfma_f32_16x16x32_bf16(afr[m2][kk], bfr[n][kk], acc[(Q)*2+m2][n], 0,0,0); \
    } \
  } \
  __builtin_amdgcn_s_setprio(0); \
}while(0)

template<int EPI>
__global__ __launch_bounds__(512, 2)
void gemmT(const unsigned short* __restrict__ A, const unsigned short* __restrict__ B,
           const float* __restrict__ bias,
           float* __restrict__ Cf, unsigned short* __restrict__ Ch,
           int M, int N, int K,
           const int* __restrict__ off, long long strideBz, long long strideBiasz)
{
  __shared__ char smem[131072];
  int z = blockIdx.z;
  int rowbase = 0, Mz = M;
  if (off){ rowbase = off[z]; Mz = off[z+1] - rowbase; }
  int row0 = blockIdx.y * 256;
  if (row0 >= Mz) return;
  int col0 = blockIdx.x * 256;
  const unsigned short* Ab = A + (size_t)(rowbase + row0) * K;
  const unsigned short* Bb = B + (size_t)z * strideBz + (size_t)col0 * K;
  const float* biasz = bias + (size_t)z * strideBiasz;

  int tid = threadIdx.x;
  int lane = tid & 63, w = tid >> 6;
  int lrow = lane & 15, lg = lane >> 4;
  int wm = w >> 2, wn = w & 3;

  f32x4 acc[8][4];
  #pragma unroll
  for (int i=0;i<8;i++){
    #pragma unroll
    for (int j=0;j<4;j++) acc[i][j] = f32x4{0.f,0.f,0.f,0.f};
  }
  int nkt = K >> 6;
  // half-tiles: H0 = A rows 0-127, H1 = A rows 128-255, H2 = B 0-127, H3 = B 128-255
  auto stage = [&](int kt2, int H){
    if (kt2 >= nkt) return;
    char* sl = smem + (kt2 & 1) * 65536 + H * 16384;
    int k0 = kt2 << 6;
    const unsigned short* src = (H < 2) ? Ab : Bb;
    int rbase = (H & 1) * 128;
    #pragma unroll
    for (int i=0;i<2;i++){
      int si = i*512 + tid;
      int r = si >> 3, kb = (si & 7) ^ (r & 7);
      gload_lds16(src + (size_t)(rbase + r)*K + k0 + kb*8, sl + si*16);
    }
  };
  // prologue: kt0 all 4 halves + kt1 B-halves; kt1 A deferred to iter0 P0
  stage(0,0); stage(0,1); stage(0,2); stage(0,3);
  stage(1,2); stage(1,3);
  asm volatile("s_waitcnt vmcnt(4)" ::: "memory");
  BAR();
  for (int kt = 0; kt < nkt; kt++){
    char* sA = smem + (kt & 1) * 65536;
    char* sB = sA + 32768;
    short8 bfr[4][2], afr[2][2];
    // ---- P0: all B-frags + A quad0; stage kt+1 A-lo + A-hi
    #pragma unroll
    for (int n=0;n<4;n++){
      int ct = wn*64 + n*16 + lrow;
      #pragma unroll
      for (int kk=0;kk<2;kk++)
        bfr[n][kk] = *(const short8*)(sB + ct*128 + (((lg+kk*4)^(ct&7))<<4));
    }
    READ_AFR(0);
    stage(kt+1, 0); stage(kt+1, 1);
    BAR();
    QUADP(0);
    BAR();
    // ---- P1: A quad1; stage B[kt+2]-lo
    READ_AFR(1);
    stage(kt+2, 2);
    BAR();
    QUADP(1);
    BAR();
    // ---- P2: A quad2; stage B[kt+2]-hi
    READ_AFR(2);
    stage(kt+2, 3);
    BAR();
    QUADP(2);
    BAR();
    // ---- P3: A quad3; counted vmcnt(4) -> A[kt+1],B[kt+1] landed
    READ_AFR(3);
    if (kt + 2 < nkt) { asm volatile("s_waitcnt vmcnt(4)" ::: "memory"); }
    else              { asm volatile("s_waitcnt vmcnt(0)" ::: "memory"); }
    BAR();
    QUADP(3);
    BAR();
  }
  #pragma unroll
  for (int m=0;m<8;m++){
    #pragma unroll
    for (int j=0;j<4;j++){
      int row = row0 + wm*128 + m*16 + lg*4 + j;
      if (row < Mz){
        size_t rg = (size_t)(rowbase + row);
        if constexpr (EPI == 2){
          #pragma unroll
          for (int nf=0;nf<4;nf+=2){
            int pcol = col0 + wn*64 + nf*16;
            int scol = ((pcol>>5)<<4) + lrow;
            float av = acc[m][nf][j]   + biasz[scol];
            float gv = acc[m][nf+1][j] + biasz[2048 + scol];
            float sg = gv / (1.f + __expf(-gv));
            Ch[rg*2048 + scol] = f2bf(av * sg);
          }
        } else {
          #pragma unroll
          for (int n=0;n<4;n++){
            int col = col0 + wn*64 + n*16 + lrow;
            float v = acc[m][n][j] + biasz[col];
            size_t idx = rg * N + col;
            if constexpr (EPI == 0) Cf[idx] = v;
            else                    Ch[idx] = f2bf(v);
          }
        }
      }
    }
  }
}

// ---------------------------------------------------------------------------
// Legacy 128x128 GEMM for the small proj matmul: +resid, fp32+bf16 out
__global__ __launch_bounds__(256)
void gemm_proj(const unsigned short* __restrict__ A, const unsigned short* __restrict__ B,
               const float* __restrict__ bias,
               float* __restrict__ Cf, unsigned short* __restrict__ Ch,
               const float* __restrict__ resid, int M, int N, int K)
{
  __shared__ char smem[32768];
  char* smA = smem; char* smB = smem + 16384;
  int row0 = blockIdx.y * 128;
  int col0 = blockIdx.x * 128;
  int t = threadIdx.x, w = t>>6, lane = t&63;
  int lrow = lane&15, lg = lane>>4;
  int wr = w>>1, wc = w&1;

  f32x4 acc[4][4];
  #pragma unroll
  for (int i=0;i<4;i++){
    #pragma unroll
    for (int j=0;j<4;j++) acc[i][j] = f32x4{0.f,0.f,0.f,0.f};
  }
  const size_t Abase = (size_t)row0 * K;
  const size_t Bbase = (size_t)col0 * K;
  int nkt = K >> 6;
  for (int kt=0; kt<nkt; kt++){
    __syncthreads();
    int k0 = kt*64;
    #pragma unroll
    for (int i=0;i<4;i++){
      int s = (i*4 + w)*64 + lane;
      int r = s>>3;
      int kb = (s&7) ^ (r&7);
      gload_lds16(A + Abase + (size_t)r*K + k0 + kb*8, smA + (size_t)(i*4+w)*1024);
      gload_lds16(B + Bbase + (size_t)r*K + k0 + kb*8, smB + (size_t)(i*4+w)*1024);
    }
    __syncthreads();
    #pragma unroll
    for (int ks=0; ks<2; ks++){
      short8 af[4], bf[4];
      int kbb = lg + ks*4;
      #pragma unroll
      for (int m=0;m<4;m++){
        int rt = wr*64 + m*16 + lrow;
        af[m] = *(const short8*)(smA + rt*128 + ((kbb ^ (rt&7))<<4));
      }
      #pragma unroll
      for (int n=0;n<4;n++){
        int rt = wc*64 + n*16 + lrow;
        bf[n] = *(const short8*)(smB + rt*128 + ((kbb ^ (rt&7))<<4));
      }
      #pragma unroll
      for (int m=0;m<4;m++){
        #pragma unroll
        for (int n=0;n<4;n++)
          acc[m][n] = __builtin_amdgcn_mfma_f32_16x16x32_bf16(af[m], bf[n], acc[m][n], 0,0,0);
      }
    }
  }
  #pragma unroll
  for (int m=0;m<4;m++){
    int rloc = wr*64 + m*16 + lg*4;
    #pragma unroll
    for (int j=0;j<4;j++){
      int row = row0 + rloc + j;
      size_t rg = (size_t)row;
      #pragma unroll
      for (int n=0;n<4;n++){
        int col = col0 + wc*64 + n*16 + lrow;
        float v = acc[m][n][j] + bias[col];
        size_t idx = rg * N + col;
        v += resid[idx];
        Cf[idx] = v;
        Ch[idx] = f2bf(v);
      }
    }
  }
}

// ---------------------------------------------------------------------------
__global__ __launch_bounds__(256)
void prep_qkv(const float* __restrict__ qkv, const float* __restrict__ alpha,
              unsigned short* __restrict__ q_s, unsigned short* __restrict__ k_hat,
              unsigned short* __restrict__ v_t)
{
  int idx = blockIdx.x*4 + (threadIdx.x>>6);
  int lane = threadIdx.x & 63;
  int h = idx & 7, bt = idx >> 3;
  size_t base = (size_t)bt*1536 + h*64 + lane;
  float qv = qkv[base], kv = qkv[base+512], vv = qkv[base+1024];
  float qs2 = qv*qv, ks2 = kv*kv;
  #pragma unroll
  for (int m=1;m<64;m<<=1){ qs2 += __shfl_xor(qs2, m); ks2 += __shfl_xor(ks2, m); }
  float qh = qv / (sqrtf(qs2) + 1e-5f) * alpha[h];
  float kh = kv / (sqrtf(ks2) + 1e-5f);
  int b = bt >> 10, tt = bt & 1023;
  size_t hb = ((size_t)(b*8+h))*1024*64;
  q_s[hb + (size_t)tt*64 + lane] = f2bf(qh);
  k_hat[hb + (size_t)tt*64 + lane] = f2bf(kh);
  v_t[((size_t)(b*8+h)*64 + lane)*1024 + tt] = f2bf(vv);
}

// ---------------------------------------------------------------------------
// Flash attention, 64-row q-tiles (grid 16x16 = 256 blocks).
__global__ __launch_bounds__(256)
void attn_k(const unsigned short* __restrict__ q_s, const unsigned short* __restrict__ k_hat,
            const unsigned short* __restrict__ v_t, unsigned short* __restrict__ y)
{
  __shared__ char sm[51200];
  char* smK = sm + 18432;
  char* smV = sm + 34816;
  int qt = blockIdx.x, bh = blockIdx.y;
  int b = bh>>3, h = bh&7;
  int t = threadIdx.x, w = t>>6, lane = t&63;
  int lrow = lane&15, lg = lane>>4;
  int q0 = qt*64;
  const size_t hQK = (size_t)bh*1024*64;
  const size_t hV  = (size_t)bh*64*1024;

  #pragma unroll
  for (int i=0;i<2;i++){
    int si = i*256 + t;
    int r = si>>3, kb = (si&7)^(r&7);
    gload_lds16(q_s + hQK + (size_t)(q0+r)*64 + kb*8, sm + (size_t)si*16);
  }
  __syncthreads();
  short8 qf[2];
  #pragma unroll
  for (int ks=0;ks<2;ks++){
    int rt = w*16 + lrow;
    int kbb = lg + ks*4;
    qf[ks] = *(const short8*)(sm + rt*128 + ((kbb^(rt&7))<<4));
  }
  f32x4 oacc[4];
  #pragma unroll
  for (int j=0;j<4;j++) oacc[j] = f32x4{0.f,0.f,0.f,0.f};
  float mrun[4], lrun[4];
  #pragma unroll
  for (int j=0;j<4;j++){ mrun[j] = -1e30f; lrun[j] = 0.f; }
  char* Pw = sm + w*2304;

  int ktmax = (q0 + 63) >> 7;
  for (int kt=0; kt<=ktmax; kt++){
    __syncthreads();
    int t0 = kt*128;
    #pragma unroll
    for (int i=0;i<4;i++){
      int s = (i*4+w)*64 + lane;
      int r = s>>3, kb = (s&7)^(r&7);
      gload_lds16(k_hat + hQK + (size_t)(t0+r)*64 + kb*8, smK + (size_t)(i*4+w)*1024);
    }
    #pragma unroll
    for (int i=0;i<4;i++){
      int s = (i*4+w)*64 + lane;
      int d = s>>4, kb2 = s&15;
      int kb = kb2 ^ (d&7);
      gload_lds16(v_t + hV + (size_t)d*1024 + t0 + kb*8, smV + (size_t)(i*4+w)*1024);
    }
    __syncthreads();

    f32x4 sacc[8];
    #pragma unroll
    for (int j=0;j<8;j++) sacc[j] = f32x4{0.f,0.f,0.f,0.f};
    #pragma unroll
    for (int ks=0;ks<2;ks++){
      short8 kf[8];
      int kbb = lg + ks*4;
      #pragma unroll
      for (int nf=0;nf<8;nf++){
        int rt = nf*16+lrow;
        kf[nf] = *(const short8*)(smK + rt*128 + ((kbb^(rt&7))<<4));
      }
      #pragma unroll
      for (int nf=0;nf<8;nf++)
        sacc[nf] = __builtin_amdgcn_mfma_f32_16x16x32_bf16(qf[ks], kf[nf], sacc[nf], 0,0,0);
    }
    if (kt == ktmax){
      #pragma unroll
      for (int nf=0;nf<8;nf++){
        #pragma unroll
        for (int j=0;j<4;j++){
          int qi = q0 + w*16 + lg*4 + j;
          int ki = t0 + nf*16 + lrow;
          if (ki > qi) sacc[nf][j] = -1e30f;
        }
      }
    }
    #pragma unroll
    for (int j=0;j<4;j++){
      float mx = sacc[0][j];
      #pragma unroll
      for (int nf=1;nf<8;nf++) mx = fmaxf(mx, sacc[nf][j]);
      #pragma unroll
      for (int m=1;m<16;m<<=1) mx = fmaxf(mx, __shfl_xor(mx, m));
      float mnew = fmaxf(mrun[j], mx);
      float sc = __expf(mrun[j] - mnew);
      float rs = 0.f;
      #pragma unroll
      for (int nf=0;nf<8;nf++){
        float p = __expf(sacc[nf][j] - mnew);
        sacc[nf][j] = p; rs += p;
      }
      #pragma unroll
      for (int m=1;m<16;m<<=1) rs += __shfl_xor(rs, m);
      lrun[j] = lrun[j]*sc + rs;
      mrun[j] = mnew;
      #pragma unroll
      for (int n2=0;n2<4;n2++) oacc[n2][j] *= sc;
    }
    #pragma unroll
    for (int half=0; half<2; half++){
      #pragma unroll
      for (int nfh=0;nfh<4;nfh++){
        int nf = half*4 + nfh;
        #pragma unroll
        for (int j=0;j<4;j++){
          int row = lg*4 + j;
          int col = nfh*16 + lrow;
          *(unsigned short*)(Pw + (row*72 + col)*2) = f2bf(sacc[nf][j]);
        }
      }
      #pragma unroll
      for (int k2=0;k2<2;k2++){
        int ks2 = half*2 + k2;
        short8 pf, vf[4];
        pf = *(const short8*)(Pw + lrow*144 + lg*16 + k2*64);
        #pragma unroll
        for (int n2=0;n2<4;n2++){
          int d = n2*16+lrow;
          int kbb2 = lg + ks2*4;
          vf[n2] = *(const short8*)(smV + d*256 + ((kbb2^(d&7))<<4));
        }
        #pragma unroll
        for (int n2=0;n2<4;n2++)
          oacc[n2] = __builtin_amdgcn_mfma_f32_16x16x32_bf16(pf, vf[n2], oacc[n2], 0,0,0);
      }
    }
  }
  #pragma unroll
  for (int n2=0;n2<4;n2++){
    #pragma unroll
    for (int j=0;j<4;j++){
      float v = oacc[n2][j] / lrun[j];
      int qi = q0 + w*16 + lg*4 + j;
      int d = n2*16 + lrow;
      y[((size_t)(b*1024+qi))*512 + h*64 + d] = f2bf(v);
    }
  }
}

// ---------------------------------------------------------------------------
__global__ __launch_bounds__(256)
void router_topk(const float* __restrict__ x2f, const float* __restrict__ rw,
                 const float* __restrict__ rb, float* __restrict__ gates)
{
  int tkn = blockIdx.x*4 + (threadIdx.x>>6);
  int lane = threadIdx.x & 63;
  int e = lane & 15, p = lane >> 4;
  const float* xr = x2f + (size_t)tkn*512;
  float part = 0.f;
  for (int d = p*128; d < p*128+128; d++)
    part += xr[d] * rw[d*16 + e];
  part += __shfl_xor(part, 16);
  part += __shfl_xor(part, 32);
  float logit = part + rb[e];
  float mx = logit;
  #pragma unroll
  for (int m=1;m<16;m<<=1) mx = fmaxf(mx, __shfl_xor(mx, m));
  float ex = __expf(logit - mx);
  float sm = ex;
  #pragma unroll
  for (int m=1;m<16;m<<=1) sm += __shfl_xor(sm, m);
  float prob = ex / sm;
  bool taken = false;
  float ssum = 0.f;
  #pragma unroll
  for (int r=0;r<8;r++){
    float cv = taken ? -1.f : prob;
    int ci = e;
    #pragma unroll
    for (int m=1;m<16;m<<=1){
      float ov = __shfl_xor(cv, m);
      int oi = __shfl_xor(ci, m);
      if (ov > cv || (ov == cv && oi < ci)){ cv = ov; ci = oi; }
    }
    if (e == ci) taken = true;
    ssum += cv;
  }
  if (lane < 16)
    gates[(size_t)tkn*16 + e] = taken ? prob / ssum : 0.f;
}

// ---------------------------------------------------------------------------
__global__ void listbuild(const float* __restrict__ gates, int* __restrict__ list,
                          int* __restrict__ slot, int* __restrict__ cnt)
{
  int e = blockIdx.x;
  int tid = threadIdx.x, w = tid>>6, lane = tid&63;
  __shared__ int sbase;
  __shared__ int wsum[4];
  if (tid==0) sbase = 0;
  __syncthreads();
  for (int c=0;c<8;c++){
    int tk = c*256 + tid;
    bool flag = gates[(size_t)tk*16 + e] > 0.f;
    unsigned long long bal = __ballot(flag);
    if (lane==0) wsum[w] = (int)__popcll(bal);
    __syncthreads();
    int wpref = 0;
    for (int i=0;i<w;i++) wpref += wsum[i];
    int tot = wsum[0]+wsum[1]+wsum[2]+wsum[3];
    int lpref = (int)__popcll(bal & ((1ull<<lane)-1ull));
    if (flag){
      int pos = sbase + wpref + lpref;
      list[e*2048 + pos] = tk;
      slot[(size_t)tk*16 + e] = pos;
    }
    __syncthreads();
    if (tid==0) sbase += tot;
    __syncthreads();
  }
  if (tid==0) cnt[e] = sbase;
}

__global__ void prefix_off(const int* __restrict__ cnt, int* __restrict__ off){
  if (threadIdx.x==0 && blockIdx.x==0){
    int a=0;
    for (int e=0;e<16;e++){ off[e]=a; a+=cnt[e]; }
    off[16]=a;
  }
}

__global__ __launch_bounds__(256)
void gather_rows(const unsigned short* __restrict__ x2h, const int* __restrict__ list,
                 const int* __restrict__ cnt, const int* __restrict__ off,
                 unsigned short* __restrict__ xe)
{
  int e = blockIdx.y;
  int s = blockIdx.x*4 + (threadIdx.x>>6);
  if (s >= cnt[e]) return;
  int lane = threadIdx.x & 63;
  int tk = list[e*2048 + s];
  *(short8*)(xe + ((size_t)(off[e]+s))*512 + lane*8) =
      *(const short8*)(x2h + (size_t)tk*512 + lane*8);
}

__global__ __launch_bounds__(256)
void combine_k(const float* __restrict__ x2f, const unsigned short* __restrict__ eo,
               const float* __restrict__ gates, const int* __restrict__ slot,
               const int* __restrict__ off, float* __restrict__ out)
{
  int tkn = blockIdx.x;
  __shared__ float gs[16];
  __shared__ int rws[16];
  int tid = threadIdx.x;
  if (tid < 16){
    float g = gates[(size_t)tkn*16 + tid];
    gs[tid] = g;
    rws[tid] = (g > 0.f) ? (off[tid] + slot[(size_t)tkn*16 + tid]) : 0;
  }
  __syncthreads();
  for (int d = tid; d < 512; d += 256){
    float v = x2f[(size_t)tkn*512 + d];
    #pragma unroll
    for (int e=0;e<16;e++){
      float g = gs[e];
      if (g > 0.f) v += g * bf2f(eo[(size_t)rws[e]*512 + d]);
    }
    out[(size_t)tkn*512 + d] = v;
  }
}

// ---------------------------------------------------------------------------
extern "C" void kernel_launch(void* const* d_in, const int* in_sizes, int n_in,
                              void* d_out, int out_size, void* d_ws, size_t ws_size,
                              hipStream_t stream) {
  (void)in_sizes; (void)n_in; (void)out_size; (void)ws_size;
  const float* x    = (const float*)d_in[0];
  const float* gw   = (const float*)d_in[1];
  const float* bw   = (const float*)d_in[2];
  const float* caw  = (const float*)d_in[3];
  const float* cab  = (const float*)d_in[4];
  const float* alpha= (const float*)d_in[5];
  const float* cpw  = (const float*)d_in[6];
  const float* cpb  = (const float*)d_in[7];
  const float* rw   = (const float*)d_in[8];
  const float* rb   = (const float*)d_in[9];
  const float* w_in = (const float*)d_in[10];
  const float* b_in = (const float*)d_in[11];
  const float* w1   = (const float*)d_in[12];
  const float* b1   = (const float*)d_in[13];
  const float* w2   = (const float*)d_in[14];
  const float* b2   = (const float*)d_in[15];
  const float* w_out= (const float*)d_in[16];
  const float* b_out= (const float*)d_in[17];

  char* ws = (char*)d_ws;
  size_t o = 0;
  auto alloc = [&](size_t bytes)->char*{
    char* p = ws + o;
    o += (bytes + 255) & ~(size_t)255;
    return p;
  };
  const size_t PADROWS = 16896;  // 16384 + 256-tile overread pad
  unsigned short* wT_attn = (unsigned short*)alloc(1536ull*512*2);
  unsigned short* wT_proj = (unsigned short*)alloc(512ull*512*2);
  unsigned short* wT_in   = (unsigned short*)alloc(16ull*2048*512*2);
  unsigned short* wT1p    = (unsigned short*)alloc(16ull*4096*2048*2);
  unsigned short* wT_2    = (unsigned short*)alloc(16ull*2048*2048*2);
  unsigned short* wT_out  = (unsigned short*)alloc(16ull*512*2048*2);
  unsigned short* xn      = (unsigned short*)alloc(2048ull*512*2);
  float*          qkv     = (float*)alloc(2048ull*1536*4);
  unsigned short* q_s     = (unsigned short*)alloc(2048ull*512*2);
  unsigned short* k_hat   = (unsigned short*)alloc(2048ull*512*2);
  unsigned short* v_t     = (unsigned short*)alloc(2048ull*512*2);
  unsigned short* ybuf    = (unsigned short*)alloc(2048ull*512*2);
  float*          x2f     = (float*)alloc(2048ull*512*4);
  unsigned short* x2h     = (unsigned short*)alloc(2048ull*512*2);
  float*          gates   = (float*)alloc(2048ull*16*4);
  int*            slot    = (int*)alloc(2048ull*16*4);
  int*            list    = (int*)alloc(16ull*2048*4);
  int*            cnt     = (int*)alloc(64);
  int*            off     = (int*)alloc(256);
  unsigned short* xe      = (unsigned short*)alloc(PADROWS*512*2);   // + eo alias
  unsigned short* hbuf    = (unsigned short*)alloc(PADROWS*2048*2);  // + o alias
  unsigned short* sbuf    = (unsigned short*)alloc(PADROWS*2048*2);
  unsigned short* eobuf   = xe;   // xe dead after h-GEMM
  unsigned short* obuf    = hbuf; // hbuf dead after fused SwiGLU GEMM

  dim3 blk(256);
  dim3 blk5(512);
  // weight transposes fp32 -> bf16 [N][K] (w1 -> permuted for fused SwiGLU)
  transpose_cvt<<<dim3(1536/32, 512/32, 1), blk, 0, stream>>>(caw, wT_attn, 512, 1536);
  transpose_cvt<<<dim3(512/32, 512/32, 1), blk, 0, stream>>>(cpw, wT_proj, 512, 512);
  transpose_cvt<<<dim3(2048/32, 512/32, 16), blk, 0, stream>>>(w_in, wT_in, 512, 2048);
  transpose_cvt_w1<<<dim3(4096/32, 2048/32, 16), blk, 0, stream>>>(w1, wT1p);
  transpose_cvt<<<dim3(2048/32, 2048/32, 16), blk, 0, stream>>>(w2, wT_2, 2048, 2048);
  transpose_cvt<<<dim3(512/32, 2048/32, 16), blk, 0, stream>>>(w_out, wT_out, 2048, 512);

  rmsnorm_k<<<512, blk, 0, stream>>>(x, gw, bw, xn);
  gemmT<0><<<dim3(6, 8, 1), blk5, 0, stream>>>(xn, wT_attn, cab, qkv, nullptr,
                                               2048, 1536, 512, nullptr, 0, 0);
  prep_qkv<<<4096, blk, 0, stream>>>(qkv, alpha, q_s, k_hat, v_t);
  attn_k<<<dim3(16,16), blk, 0, stream>>>(q_s, k_hat, v_t, ybuf);
  gemm_proj<<<dim3(4,16,1), blk, 0, stream>>>(ybuf, wT_proj, cpb, x2f, x2h, x, 2048, 512, 512);
  router_topk<<<512, blk, 0, stream>>>(x2f, rw, rb, gates);
  listbuild<<<16, blk, 0, stream>>>(gates, list, slot, cnt);
  prefix_off<<<1, 64, 0, stream>>>(cnt, off);
  gather_rows<<<dim3(512,16), blk, 0, stream>>>(x2h, list, cnt, off, xe);

  // experts (batched over z = expert, rows compacted via off[])
  gemmT<1><<<dim3(8,8,16), blk5, 0, stream>>>(xe, wT_in, b_in, nullptr, hbuf,
                                              0, 2048, 512, off, 2048ll*512, 2048);
  gemmT<2><<<dim3(16,8,16), blk5, 0, stream>>>(hbuf, wT1p, b1, nullptr, sbuf,
                                               0, 4096, 2048, off, 4096ll*2048, 4096);
  gemmT<1><<<dim3(8,8,16), blk5, 0, stream>>>(sbuf, wT_2, b2, nullptr, obuf,
                                              0, 2048, 2048, off, 2048ll*2048, 2048);
  gemmT<1><<<dim3(2,8,16), blk5, 0, stream>>>(obuf, wT_out, b_out, nullptr, eobuf,
                                              0, 512, 2048, off, 512ll*2048, 512);
  combine_k<<<2048, blk, 0, stream>>>(x2f, eobuf, gates, slot, off, (float*)d_out);
}

// Round 11
// 1094.065 us; speedup vs baseline: 1.0213x; 1.0100x over previous
//
#include <hip/hip_runtime.h>
#include <stdint.h>

#define DEVI __device__ __forceinline__
#define FENCE() asm volatile("" ::: "memory")
#define BAR() do{ FENCE(); __builtin_amdgcn_s_barrier(); FENCE(); }while(0)

typedef short short8 __attribute__((ext_vector_type(8)));
typedef short short4v __attribute__((ext_vector_type(4)));
typedef float f32x4 __attribute__((ext_vector_type(4)));

DEVI float bf2f(unsigned short s){ union{unsigned u; float f;} x; x.u = ((unsigned)s)<<16; return x.f; }
DEVI unsigned short f2bf(float f){ union{float f; unsigned u;} x; x.f=f; unsigned r = x.u + 0x7fff + ((x.u>>16)&1); return (unsigned short)(r>>16); }

DEVI void gload_lds16(const void* g, void* l){
  __builtin_amdgcn_global_load_lds((const __attribute__((address_space(1))) unsigned int*)g,
                                   (__attribute__((address_space(3))) unsigned int*)l, 16, 0, 0);
}

// ---------------------------------------------------------------------------
// Merged weight-prep kernel: all fp32->bf16 [N][K] transposes + permuted w1
// + rmsnorm, as one dispatch (jobs are independent; job table on blockIdx.x).
DEVI void tr_tile(const float* __restrict__ src, unsigned short* __restrict__ dst,
                  int K, int N, int kb, int nb, int t, float (*tile)[33])
{
  int tr = t>>3, tc = (t&7)*4;
  float4 v = *(const float4*)(src + (size_t)(kb+tr)*N + nb + tc);
  tile[tr][tc+0]=v.x; tile[tr][tc+1]=v.y; tile[tr][tc+2]=v.z; tile[tr][tc+3]=v.w;
  __syncthreads();
  short4v ov;
  ov[0] = (short)f2bf(tile[tc+0][tr]);
  ov[1] = (short)f2bf(tile[tc+1][tr]);
  ov[2] = (short)f2bf(tile[tc+2][tr]);
  ov[3] = (short)f2bf(tile[tc+3][tr]);
  *(short4v*)(dst + (size_t)(nb+tr)*K + kb + tc) = ov;
}

__global__ __launch_bounds__(256)
void prep_all(const float* __restrict__ caw, const float* __restrict__ cpw,
              const float* __restrict__ w_in, const float* __restrict__ w1,
              const float* __restrict__ w2, const float* __restrict__ w_out,
              unsigned short* __restrict__ wT_attn, unsigned short* __restrict__ wT_proj,
              unsigned short* __restrict__ wT_in, unsigned short* __restrict__ wT1p,
              unsigned short* __restrict__ wT_2, unsigned short* __restrict__ wT_out,
              const float* __restrict__ x, const float* __restrict__ gw,
              const float* __restrict__ bw, unsigned short* __restrict__ xn)
{
  __shared__ float tile[32][33];
  int bid = blockIdx.x;
  int t = threadIdx.x;
  if (bid < 768){                 // attn W: K=512, N=1536, nx=48
    int xb = bid % 48, yb = bid / 48;
    tr_tile(caw, wT_attn, 512, 1536, yb*32, xb*32, t, tile); return;
  }
  bid -= 768;
  if (bid < 256){                 // proj W: 512x512, nx=16
    int xb = bid % 16, yb = bid / 16;
    tr_tile(cpw, wT_proj, 512, 512, yb*32, xb*32, t, tile); return;
  }
  bid -= 256;
  if (bid < 16384){               // w_in: K=512, N=2048, nx=64, ny=16, z=16
    int z = bid >> 10, r = bid & 1023;
    int xb = r % 64, yb = r / 64;
    tr_tile(w_in + (size_t)z*512*2048, wT_in + (size_t)z*2048*512,
            512, 2048, yb*32, xb*32, t, tile); return;
  }
  bid -= 16384;
  if (bid < 131072){              // w1 permuted: nx=128, ny=64, z=16
    int z = bid >> 13, r = bid & 8191;
    int xb = r % 128, yb = r / 128;
    const float* src = w1 + (size_t)z*2048*4096;
    unsigned short* dst = wT1p + (size_t)z*4096*2048;
    int np0 = xb*32, k0 = yb*32, g = np0 >> 5;
    int trr = t>>3, tc = (t&7)*4;
    int srccol = (tc < 16) ? (g*16 + tc) : (2048 + g*16 + (tc-16));
    float4 v = *(const float4*)(src + (size_t)(k0+trr)*4096 + srccol);
    tile[trr][tc+0]=v.x; tile[trr][tc+1]=v.y; tile[trr][tc+2]=v.z; tile[trr][tc+3]=v.w;
    __syncthreads();
    short4v ov;
    ov[0] = (short)f2bf(tile[tc+0][trr]);
    ov[1] = (short)f2bf(tile[tc+1][trr]);
    ov[2] = (short)f2bf(tile[tc+2][trr]);
    ov[3] = (short)f2bf(tile[tc+3][trr]);
    *(short4v*)(dst + (size_t)(np0+trr)*2048 + k0 + tc) = ov;
    return;
  }
  bid -= 131072;
  if (bid < 65536){               // w2: 2048x2048, nx=64, ny=64, z=16
    int z = bid >> 12, r = bid & 4095;
    int xb = r % 64, yb = r / 64;
    tr_tile(w2 + (size_t)z*2048*2048, wT_2 + (size_t)z*2048*2048,
            2048, 2048, yb*32, xb*32, t, tile); return;
  }
  bid -= 65536;
  if (bid < 16384){               // w_out: K=2048, N=512, nx=16, ny=64, z=16
    int z = bid >> 10, r = bid & 1023;
    int xb = r % 16, yb = r / 16;
    tr_tile(w_out + (size_t)z*2048*512, wT_out + (size_t)z*512*2048,
            2048, 512, yb*32, xb*32, t, tile); return;
  }
  bid -= 16384;
  {                               // rmsnorm: 512 blocks x 4 rows
    int row = bid*4 + (t>>6);
    int lane = t & 63;
    const float* xr = x + (size_t)row*512 + lane*8;
    float4 a = *(const float4*)xr;
    float4 c = *(const float4*)(xr+4);
    float ss = a.x*a.x+a.y*a.y+a.z*a.z+a.w*a.w + c.x*c.x+c.y*c.y+c.z*c.z+c.w*c.w;
    #pragma unroll
    for (int m=1;m<64;m<<=1) ss += __shfl_xor(ss, m);
    float inv = 1.0f / sqrtf(ss*(1.f/512.f) + 1e-6f);
    const float* gr = gw + lane*8; const float* br = bw + lane*8;
    float4 g0=*(const float4*)gr, g1=*(const float4*)(gr+4);
    float4 b0=*(const float4*)br, b1=*(const float4*)(br+4);
    short8 o;
    o[0]=(short)f2bf(a.x*inv*g0.x + b0.x);
    o[1]=(short)f2bf(a.y*inv*g0.y + b0.y);
    o[2]=(short)f2bf(a.z*inv*g0.z + b0.z);
    o[3]=(short)f2bf(a.w*inv*g0.w + b0.w);
    o[4]=(short)f2bf(c.x*inv*g1.x + b1.x);
    o[5]=(short)f2bf(c.y*inv*g1.y + b1.y);
    o[6]=(short)f2bf(c.z*inv*g1.z + b1.z);
    o[7]=(short)f2bf(c.w*inv*g1.w + b1.w);
    *(short8*)(xn + (size_t)row*512 + lane*8) = o;
  }
}

// ---------------------------------------------------------------------------
// 256x256 pipelined GEMM, 4 phases/K-tile (round-10 proven engine).
// EPI: 0 = fp32 out + bias; 1 = bf16 out + bias; 2 = fused SwiGLU (permuted
//      W1, N=4096 acc -> 2048-col bf16 out); 3 = fused qkv head-norm epilogue
//      (q_s = q_hat*alpha, k_hat, v transposed; no C buffer written)
#define READ_AFR(Q) do{ \
  _Pragma("unroll") \
  for (int m2=0;m2<2;m2++){ \
    int rt = wm*128 + ((Q)*2+m2)*16 + lrow; \
    _Pragma("unroll") \
    for (int kk=0;kk<2;kk++) \
      afr[m2][kk] = *(const short8*)(sA + rt*128 + (((lg+kk*4)^(rt&7))<<4)); \
  } \
}while(0)

#define QUADP(Q) do{ \
  __builtin_amdgcn_s_setprio(1); \
  _Pragma("unroll") \
  for (int m2=0;m2<2;m2++){ \
    _Pragma("unroll") \
    for (int n=0;n<4;n++){ \
      _Pragma("unroll") \
      for (int kk=0;kk<2;kk++) \
        acc[(Q)*2+m2][n] = __builtin_amdgcn_mfma_f32_16x16x32_bf16(afr[m2][kk], bfr[n][kk], acc[(Q)*2+m2][n], 0,0,0); \
    } \
  } \
  __builtin_amdgcn_s_setprio(0); \
}while(0)

template<int EPI>
__global__ __launch_bounds__(512, 2)
void gemmT(const unsigned short* __restrict__ A, const unsigned short* __restrict__ B,
           const float* __restrict__ bias,
           float* __restrict__ Cf, unsigned short* __restrict__ Ch,
           int M, int N, int K,
           const int* __restrict__ off, long long strideBz, long long strideBiasz,
           const float* __restrict__ alpha, unsigned short* __restrict__ oq,
           unsigned short* __restrict__ ok, unsigned short* __restrict__ ov)
{
  __shared__ char smem[131072];
  int z = blockIdx.z;
  int rowbase = 0, Mz = M;
  if (off){ rowbase = off[z]; Mz = off[z+1] - rowbase; }
  int row0 = blockIdx.y * 256;
  if (row0 >= Mz) return;
  int col0 = blockIdx.x * 256;
  const unsigned short* Ab = A + (size_t)(rowbase + row0) * K;
  const unsigned short* Bb = B + (size_t)z * strideBz + (size_t)col0 * K;
  const float* biasz = bias + (size_t)z * strideBiasz;

  int tid = threadIdx.x;
  int lane = tid & 63, w = tid >> 6;
  int lrow = lane & 15, lg = lane >> 4;
  int wm = w >> 2, wn = w & 3;

  f32x4 acc[8][4];
  #pragma unroll
  for (int i=0;i<8;i++){
    #pragma unroll
    for (int j=0;j<4;j++) acc[i][j] = f32x4{0.f,0.f,0.f,0.f};
  }
  int nkt = K >> 6;
  auto stage = [&](int kt2, int H){
    if (kt2 >= nkt) return;
    char* sl = smem + (kt2 & 1) * 65536 + H * 16384;
    int k0 = kt2 << 6;
    const unsigned short* src = (H < 2) ? Ab : Bb;
    int rbase = (H & 1) * 128;
    #pragma unroll
    for (int i=0;i<2;i++){
      int si = i*512 + tid;
      int r = si >> 3, kb = (si & 7) ^ (r & 7);
      gload_lds16(src + (size_t)(rbase + r)*K + k0 + kb*8, sl + si*16);
    }
  };
  stage(0,0); stage(0,1); stage(0,2); stage(0,3);
  stage(1,2); stage(1,3);
  asm volatile("s_waitcnt vmcnt(4)" ::: "memory");
  BAR();
  for (int kt = 0; kt < nkt; kt++){
    char* sA = smem + (kt & 1) * 65536;
    char* sB = sA + 32768;
    short8 bfr[4][2], afr[2][2];
    // ---- P0: all B-frags + A quad0; stage kt+1 A-lo + A-hi
    #pragma unroll
    for (int n=0;n<4;n++){
      int ct = wn*64 + n*16 + lrow;
      #pragma unroll
      for (int kk=0;kk<2;kk++)
        bfr[n][kk] = *(const short8*)(sB + ct*128 + (((lg+kk*4)^(ct&7))<<4));
    }
    READ_AFR(0);
    stage(kt+1, 0); stage(kt+1, 1);
    BAR();
    QUADP(0);
    BAR();
    // ---- P1: A quad1; stage B[kt+2]-lo
    READ_AFR(1);
    stage(kt+2, 2);
    BAR();
    QUADP(1);
    BAR();
    // ---- P2: A quad2; stage B[kt+2]-hi
    READ_AFR(2);
    stage(kt+2, 3);
    BAR();
    QUADP(2);
    BAR();
    // ---- P3: A quad3; counted vmcnt(4) -> A[kt+1],B[kt+1] landed
    READ_AFR(3);
    if (kt + 2 < nkt) { asm volatile("s_waitcnt vmcnt(4)" ::: "memory"); }
    else              { asm volatile("s_waitcnt vmcnt(0)" ::: "memory"); }
    BAR();
    QUADP(3);
    BAR();
  }
  if constexpr (EPI == 3){
    // fused qkv head-norm: wave's 64 cols = one head-section (64 | wn*64)
    int tcol = col0 + wn*64;
    int type = tcol >> 9;           // 0=q, 1=k, 2=v
    int hd = (tcol >> 6) & 7;
    float al = alpha[hd];
    #pragma unroll
    for (int m=0;m<8;m++){
      #pragma unroll
      for (int j=0;j<4;j++){
        int row = row0 + wm*128 + m*16 + lg*4 + j;
        float v4[4]; float ss = 0.f;
        #pragma unroll
        for (int n=0;n<4;n++){
          int col = tcol + n*16 + lrow;
          v4[n] = acc[m][n][j] + biasz[col];
          ss += v4[n]*v4[n];
        }
        ss += __shfl_xor(ss,1); ss += __shfl_xor(ss,2);
        ss += __shfl_xor(ss,4); ss += __shfl_xor(ss,8);
        int b = row >> 10, tt = row & 1023;
        size_t hb = ((size_t)(b*8+hd))*65536;
        if (type == 0){
          float sc = al / (sqrtf(ss) + 1e-5f);
          #pragma unroll
          for (int n=0;n<4;n++)
            oq[hb + (size_t)tt*64 + n*16 + lrow] = f2bf(v4[n]*sc);
        } else if (type == 1){
          float sc = 1.f / (sqrtf(ss) + 1e-5f);
          #pragma unroll
          for (int n=0;n<4;n++)
            ok[hb + (size_t)tt*64 + n*16 + lrow] = f2bf(v4[n]*sc);
        } else {
          #pragma unroll
          for (int n=0;n<4;n++)
            ov[((size_t)(b*8+hd)*64 + n*16 + lrow)*1024 + tt] = f2bf(v4[n]);
        }
      }
    }
  } else {
    #pragma unroll
    for (int m=0;m<8;m++){
      #pragma unroll
      for (int j=0;j<4;j++){
        int row = row0 + wm*128 + m*16 + lg*4 + j;
        if (row < Mz){
          size_t rg = (size_t)(rowbase + row);
          if constexpr (EPI == 2){
            #pragma unroll
            for (int nf=0;nf<4;nf+=2){
              int pcol = col0 + wn*64 + nf*16;
              int scol = ((pcol>>5)<<4) + lrow;
              float av = acc[m][nf][j]   + biasz[scol];
              float gv = acc[m][nf+1][j] + biasz[2048 + scol];
              float sg = gv / (1.f + __expf(-gv));
              Ch[rg*2048 + scol] = f2bf(av * sg);
            }
          } else {
            #pragma unroll
            for (int n=0;n<4;n++){
              int col = col0 + wn*64 + n*16 + lrow;
              float v = acc[m][n][j] + biasz[col];
              size_t idx = rg * N + col;
              if constexpr (EPI == 0) Cf[idx] = v;
              else                    Ch[idx] = f2bf(v);
            }
          }
        }
      }
    }
  }
}

// ---------------------------------------------------------------------------
// Legacy 128x128 GEMM for the small proj matmul: +resid, fp32+bf16 out
__global__ __launch_bounds__(256)
void gemm_proj(const unsigned short* __restrict__ A, const unsigned short* __restrict__ B,
               const float* __restrict__ bias,
               float* __restrict__ Cf, unsigned short* __restrict__ Ch,
               const float* __restrict__ resid, int M, int N, int K)
{
  __shared__ char smem[32768];
  char* smA = smem; char* smB = smem + 16384;
  int row0 = blockIdx.y * 128;
  int col0 = blockIdx.x * 128;
  int t = threadIdx.x, w = t>>6, lane = t&63;
  int lrow = lane&15, lg = lane>>4;
  int wr = w>>1, wc = w&1;

  f32x4 acc[4][4];
  #pragma unroll
  for (int i=0;i<4;i++){
    #pragma unroll
    for (int j=0;j<4;j++) acc[i][j] = f32x4{0.f,0.f,0.f,0.f};
  }
  const size_t Abase = (size_t)row0 * K;
  const size_t Bbase = (size_t)col0 * K;
  int nkt = K >> 6;
  for (int kt=0; kt<nkt; kt++){
    __syncthreads();
    int k0 = kt*64;
    #pragma unroll
    for (int i=0;i<4;i++){
      int s = (i*4 + w)*64 + lane;
      int r = s>>3;
      int kb = (s&7) ^ (r&7);
      gload_lds16(A + Abase + (size_t)r*K + k0 + kb*8, smA + (size_t)(i*4+w)*1024);
      gload_lds16(B + Bbase + (size_t)r*K + k0 + kb*8, smB + (size_t)(i*4+w)*1024);
    }
    __syncthreads();
    #pragma unroll
    for (int ks=0; ks<2; ks++){
      short8 af[4], bf[4];
      int kbb = lg + ks*4;
      #pragma unroll
      for (int m=0;m<4;m++){
        int rt = wr*64 + m*16 + lrow;
        af[m] = *(const short8*)(smA + rt*128 + ((kbb ^ (rt&7))<<4));
      }
      #pragma unroll
      for (int n=0;n<4;n++){
        int rt = wc*64 + n*16 + lrow;
        bf[n] = *(const short8*)(smB + rt*128 + ((kbb ^ (rt&7))<<4));
      }
      #pragma unroll
      for (int m=0;m<4;m++){
        #pragma unroll
        for (int n=0;n<4;n++)
          acc[m][n] = __builtin_amdgcn_mfma_f32_16x16x32_bf16(af[m], bf[n], acc[m][n], 0,0,0);
      }
    }
  }
  #pragma unroll
  for (int m=0;m<4;m++){
    int rloc = wr*64 + m*16 + lg*4;
    #pragma unroll
    for (int j=0;j<4;j++){
      int row = row0 + rloc + j;
      size_t rg = (size_t)row;
      #pragma unroll
      for (int n=0;n<4;n++){
        int col = col0 + wc*64 + n*16 + lrow;
        float v = acc[m][n][j] + bias[col];
        size_t idx = rg * N + col;
        v += resid[idx];
        Cf[idx] = v;
        Ch[idx] = f2bf(v);
      }
    }
  }
}

// ---------------------------------------------------------------------------
// Flash attention, 64-row q-tiles (grid 16x16 = 256 blocks).
__global__ __launch_bounds__(256)
void attn_k(const unsigned short* __restrict__ q_s, const unsigned short* __restrict__ k_hat,
            const unsigned short* __restrict__ v_t, unsigned short* __restrict__ y)
{
  __shared__ char sm[51200];
  char* smK = sm + 18432;
  char* smV = sm + 34816;
  int qt = blockIdx.x, bh = blockIdx.y;
  int b = bh>>3, h = bh&7;
  int t = threadIdx.x, w = t>>6, lane = t&63;
  int lrow = lane&15, lg = lane>>4;
  int q0 = qt*64;
  const size_t hQK = (size_t)bh*1024*64;
  const size_t hV  = (size_t)bh*64*1024;

  #pragma unroll
  for (int i=0;i<2;i++){
    int si = i*256 + t;
    int r = si>>3, kb = (si&7)^(r&7);
    gload_lds16(q_s + hQK + (size_t)(q0+r)*64 + kb*8, sm + (size_t)si*16);
  }
  __syncthreads();
  short8 qf[2];
  #pragma unroll
  for (int ks=0;ks<2;ks++){
    int rt = w*16 + lrow;
    int kbb = lg + ks*4;
    qf[ks] = *(const short8*)(sm + rt*128 + ((kbb^(rt&7))<<4));
  }
  f32x4 oacc[4];
  #pragma unroll
  for (int j=0;j<4;j++) oacc[j] = f32x4{0.f,0.f,0.f,0.f};
  float mrun[4], lrun[4];
  #pragma unroll
  for (int j=0;j<4;j++){ mrun[j] = -1e30f; lrun[j] = 0.f; }
  char* Pw = sm + w*2304;

  int ktmax = (q0 + 63) >> 7;
  for (int kt=0; kt<=ktmax; kt++){
    __syncthreads();
    int t0 = kt*128;
    #pragma unroll
    for (int i=0;i<4;i++){
      int s = (i*4+w)*64 + lane;
      int r = s>>3, kb = (s&7)^(r&7);
      gload_lds16(k_hat + hQK + (size_t)(t0+r)*64 + kb*8, smK + (size_t)(i*4+w)*1024);
    }
    #pragma unroll
    for (int i=0;i<4;i++){
      int s = (i*4+w)*64 + lane;
      int d = s>>4, kb2 = s&15;
      int kb = kb2 ^ (d&7);
      gload_lds16(v_t + hV + (size_t)d*1024 + t0 + kb*8, smV + (size_t)(i*4+w)*1024);
    }
    __syncthreads();

    f32x4 sacc[8];
    #pragma unroll
    for (int j=0;j<8;j++) sacc[j] = f32x4{0.f,0.f,0.f,0.f};
    #pragma unroll
    for (int ks=0;ks<2;ks++){
      short8 kf[8];
      int kbb = lg + ks*4;
      #pragma unroll
      for (int nf=0;nf<8;nf++){
        int rt = nf*16+lrow;
        kf[nf] = *(const short8*)(smK + rt*128 + ((kbb^(rt&7))<<4));
      }
      #pragma unroll
      for (int nf=0;nf<8;nf++)
        sacc[nf] = __builtin_amdgcn_mfma_f32_16x16x32_bf16(qf[ks], kf[nf], sacc[nf], 0,0,0);
    }
    if (kt == ktmax){
      #pragma unroll
      for (int nf=0;nf<8;nf++){
        #pragma unroll
        for (int j=0;j<4;j++){
          int qi = q0 + w*16 + lg*4 + j;
          int ki = t0 + nf*16 + lrow;
          if (ki > qi) sacc[nf][j] = -1e30f;
        }
      }
    }
    #pragma unroll
    for (int j=0;j<4;j++){
      float mx = sacc[0][j];
      #pragma unroll
      for (int nf=1;nf<8;nf++) mx = fmaxf(mx, sacc[nf][j]);
      #pragma unroll
      for (int m=1;m<16;m<<=1) mx = fmaxf(mx, __shfl_xor(mx, m));
      float mnew = fmaxf(mrun[j], mx);
      float sc = __expf(mrun[j] - mnew);
      float rs = 0.f;
      #pragma unroll
      for (int nf=0;nf<8;nf++){
        float p = __expf(sacc[nf][j] - mnew);
        sacc[nf][j] = p; rs += p;
      }
      #pragma unroll
      for (int m=1;m<16;m<<=1) rs += __shfl_xor(rs, m);
      lrun[j] = lrun[j]*sc + rs;
      mrun[j] = mnew;
      #pragma unroll
      for (int n2=0;n2<4;n2++) oacc[n2][j] *= sc;
    }
    #pragma unroll
    for (int half=0; half<2; half++){
      #pragma unroll
      for (int nfh=0;nfh<4;nfh++){
        int nf = half*4 + nfh;
        #pragma unroll
        for (int j=0;j<4;j++){
          int row = lg*4 + j;
          int col = nfh*16 + lrow;
          *(unsigned short*)(Pw + (row*72 + col)*2) = f2bf(sacc[nf][j]);
        }
      }
      #pragma unroll
      for (int k2=0;k2<2;k2++){
        int ks2 = half*2 + k2;
        short8 pf, vf[4];
        pf = *(const short8*)(Pw + lrow*144 + lg*16 + k2*64);
        #pragma unroll
        for (int n2=0;n2<4;n2++){
          int d = n2*16+lrow;
          int kbb2 = lg + ks2*4;
          vf[n2] = *(const short8*)(smV + d*256 + ((kbb2^(d&7))<<4));
        }
        #pragma unroll
        for (int n2=0;n2<4;n2++)
          oacc[n2] = __builtin_amdgcn_mfma_f32_16x16x32_bf16(pf, vf[n2], oacc[n2], 0,0,0);
      }
    }
  }
  #pragma unroll
  for (int n2=0;n2<4;n2++){
    #pragma unroll
    for (int j=0;j<4;j++){
      float v = oacc[n2][j] / lrun[j];
      int qi = q0 + w*16 + lg*4 + j;
      int d = n2*16 + lrow;
      y[((size_t)(b*1024+qi))*512 + h*64 + d] = f2bf(v);
    }
  }
}

// ---------------------------------------------------------------------------
__global__ __launch_bounds__(256)
void router_topk(const float* __restrict__ x2f, const float* __restrict__ rw,
                 const float* __restrict__ rb, float* __restrict__ gates)
{
  int tkn = blockIdx.x*4 + (threadIdx.x>>6);
  int lane = threadIdx.x & 63;
  int e = lane & 15, p = lane >> 4;
  const float* xr = x2f + (size_t)tkn*512;
  float part = 0.f;
  for (int d = p*128; d < p*128+128; d++)
    part += xr[d] * rw[d*16 + e];
  part += __shfl_xor(part, 16);
  part += __shfl_xor(part, 32);
  float logit = part + rb[e];
  float mx = logit;
  #pragma unroll
  for (int m=1;m<16;m<<=1) mx = fmaxf(mx, __shfl_xor(mx, m));
  float ex = __expf(logit - mx);
  float sm = ex;
  #pragma unroll
  for (int m=1;m<16;m<<=1) sm += __shfl_xor(sm, m);
  float prob = ex / sm;
  bool taken = false;
  float ssum = 0.f;
  #pragma unroll
  for (int r=0;r<8;r++){
    float cv = taken ? -1.f : prob;
    int ci = e;
    #pragma unroll
    for (int m=1;m<16;m<<=1){
      float ov = __shfl_xor(cv, m);
      int oi = __shfl_xor(ci, m);
      if (ov > cv || (ov == cv && oi < ci)){ cv = ov; ci = oi; }
    }
    if (e == ci) taken = true;
    ssum += cv;
  }
  if (lane < 16)
    gates[(size_t)tkn*16 + e] = taken ? prob / ssum : 0.f;
}

// ---------------------------------------------------------------------------
__global__ void listbuild(const float* __restrict__ gates, int* __restrict__ list,
                          int* __restrict__ slot, int* __restrict__ cnt)
{
  int e = blockIdx.x;
  int tid = threadIdx.x, w = tid>>6, lane = tid&63;
  __shared__ int sbase;
  __shared__ int wsum[4];
  if (tid==0) sbase = 0;
  __syncthreads();
  for (int c=0;c<8;c++){
    int tk = c*256 + tid;
    bool flag = gates[(size_t)tk*16 + e] > 0.f;
    unsigned long long bal = __ballot(flag);
    if (lane==0) wsum[w] = (int)__popcll(bal);
    __syncthreads();
    int wpref = 0;
    for (int i=0;i<w;i++) wpref += wsum[i];
    int tot = wsum[0]+wsum[1]+wsum[2]+wsum[3];
    int lpref = (int)__popcll(bal & ((1ull<<lane)-1ull));
    if (flag){
      int pos = sbase + wpref + lpref;
      list[e*2048 + pos] = tk;
      slot[(size_t)tk*16 + e] = pos;
    }
    __syncthreads();
    if (tid==0) sbase += tot;
    __syncthreads();
  }
  if (tid==0) cnt[e] = sbase;
}

__global__ void prefix_off(const int* __restrict__ cnt, int* __restrict__ off){
  if (threadIdx.x==0 && blockIdx.x==0){
    int a=0;
    for (int e=0;e<16;e++){ off[e]=a; a+=cnt[e]; }
    off[16]=a;
  }
}

__global__ __launch_bounds__(256)
void gather_rows(const unsigned short* __restrict__ x2h, const int* __restrict__ list,
                 const int* __restrict__ cnt, const int* __restrict__ off,
                 unsigned short* __restrict__ xe)
{
  int e = blockIdx.y;
  int s = blockIdx.x*4 + (threadIdx.x>>6);
  if (s >= cnt[e]) return;
  int lane = threadIdx.x & 63;
  int tk = list[e*2048 + s];
  *(short8*)(xe + ((size_t)(off[e]+s))*512 + lane*8) =
      *(const short8*)(x2h + (size_t)tk*512 + lane*8);
}

__global__ __launch_bounds__(256)
void combine_k(const float* __restrict__ x2f, const unsigned short* __restrict__ eo,
               const float* __restrict__ gates, const int* __restrict__ slot,
               const int* __restrict__ off, float* __restrict__ out)
{
  int tkn = blockIdx.x;
  __shared__ float gs[16];
  __shared__ int rws[16];
  int tid = threadIdx.x;
  if (tid < 16){
    float g = gates[(size_t)tkn*16 + tid];
    gs[tid] = g;
    rws[tid] = (g > 0.f) ? (off[tid] + slot[(size_t)tkn*16 + tid]) : 0;
  }
  __syncthreads();
  for (int d = tid; d < 512; d += 256){
    float v = x2f[(size_t)tkn*512 + d];
    #pragma unroll
    for (int e=0;e<16;e++){
      float g = gs[e];
      if (g > 0.f) v += g * bf2f(eo[(size_t)rws[e]*512 + d]);
    }
    out[(size_t)tkn*512 + d] = v;
  }
}

// ---------------------------------------------------------------------------
extern "C" void kernel_launch(void* const* d_in, const int* in_sizes, int n_in,
                              void* d_out, int out_size, void* d_ws, size_t ws_size,
                              hipStream_t stream) {
  (void)in_sizes; (void)n_in; (void)out_size; (void)ws_size;
  const float* x    = (const float*)d_in[0];
  const float* gw   = (const float*)d_in[1];
  const float* bw   = (const float*)d_in[2];
  const float* caw  = (const float*)d_in[3];
  const float* cab  = (const float*)d_in[4];
  const float* alpha= (const float*)d_in[5];
  const float* cpw  = (const float*)d_in[6];
  const float* cpb  = (const float*)d_in[7];
  const float* rw   = (const float*)d_in[8];
  const float* rb   = (const float*)d_in[9];
  const float* w_in = (const float*)d_in[10];
  const float* b_in = (const float*)d_in[11];
  const float* w1   = (const float*)d_in[12];
  const float* b1   = (const float*)d_in[13];
  const float* w2   = (const float*)d_in[14];
  const float* b2   = (const float*)d_in[15];
  const float* w_out= (const float*)d_in[16];
  const float* b_out= (const float*)d_in[17];

  char* ws = (char*)d_ws;
  size_t o = 0;
  auto alloc = [&](size_t bytes)->char*{
    char* p = ws + o;
    o += (bytes + 255) & ~(size_t)255;
    return p;
  };
  const size_t PADROWS = 16896;  // 16384 + 256-tile overread pad
  unsigned short* wT_attn = (unsigned short*)alloc(1536ull*512*2);
  unsigned short* wT_proj = (unsigned short*)alloc(512ull*512*2);
  unsigned short* wT_in   = (unsigned short*)alloc(16ull*2048*512*2);
  unsigned short* wT1p    = (unsigned short*)alloc(16ull*4096*2048*2);
  unsigned short* wT_2    = (unsigned short*)alloc(16ull*2048*2048*2);
  unsigned short* wT_out  = (unsigned short*)alloc(16ull*512*2048*2);
  unsigned short* xn      = (unsigned short*)alloc(2048ull*512*2);
  unsigned short* q_s     = (unsigned short*)alloc(2048ull*512*2);
  unsigned short* k_hat   = (unsigned short*)alloc(2048ull*512*2);
  unsigned short* v_t     = (unsigned short*)alloc(2048ull*512*2);
  unsigned short* ybuf    = (unsigned short*)alloc(2048ull*512*2);
  float*          x2f     = (float*)alloc(2048ull*512*4);
  unsigned short* x2h     = (unsigned short*)alloc(2048ull*512*2);
  float*          gates   = (float*)alloc(2048ull*16*4);
  int*            slot    = (int*)alloc(2048ull*16*4);
  int*            list    = (int*)alloc(16ull*2048*4);
  int*            cnt     = (int*)alloc(64);
  int*            off     = (int*)alloc(256);
  unsigned short* xe      = (unsigned short*)alloc(PADROWS*512*2);   // + eo alias
  unsigned short* hbuf    = (unsigned short*)alloc(PADROWS*2048*2);  // + o alias
  unsigned short* sbuf    = (unsigned short*)alloc(PADROWS*2048*2);
  unsigned short* eobuf   = xe;   // xe dead after h-GEMM
  unsigned short* obuf    = hbuf; // hbuf dead after fused SwiGLU GEMM

  dim3 blk(256);
  dim3 blk5(512);
  // one merged prep dispatch: 6 weight transposes + rmsnorm
  prep_all<<<230912, blk, 0, stream>>>(caw, cpw, w_in, w1, w2, w_out,
                                       wT_attn, wT_proj, wT_in, wT1p, wT_2, wT_out,
                                       x, gw, bw, xn);

  // qkv GEMM with fused head-norm epilogue (writes q_s/k_hat/v_t directly)
  gemmT<3><<<dim3(6, 8, 1), blk5, 0, stream>>>(xn, wT_attn, cab, nullptr, nullptr,
                                               2048, 1536, 512, nullptr, 0, 0,
                                               alpha, q_s, k_hat, v_t);
  attn_k<<<dim3(16,16), blk, 0, stream>>>(q_s, k_hat, v_t, ybuf);
  gemm_proj<<<dim3(4,16,1), blk, 0, stream>>>(ybuf, wT_proj, cpb, x2f, x2h, x, 2048, 512, 512);
  router_topk<<<512, blk, 0, stream>>>(x2f, rw, rb, gates);
  listbuild<<<16, blk, 0, stream>>>(gates, list, slot, cnt);
  prefix_off<<<1, 64, 0, stream>>>(cnt, off);
  gather_rows<<<dim3(512,16), blk, 0, stream>>>(x2h, list, cnt, off, xe);

  // experts (batched over z = expert, rows compacted via off[])
  gemmT<1><<<dim3(8,8,16), blk5, 0, stream>>>(xe, wT_in, b_in, nullptr, hbuf,
                                              0, 2048, 512, off, 2048ll*512, 2048,
                                              nullptr, nullptr, nullptr, nullptr);
  gemmT<2><<<dim3(16,8,16), blk5, 0, stream>>>(hbuf, wT1p, b1, nullptr, sbuf,
                                               0, 4096, 2048, off, 4096ll*2048, 4096,
                                               nullptr, nullptr, nullptr, nullptr);
  gemmT<1><<<dim3(8,8,16), blk5, 0, stream>>>(sbuf, wT_2, b2, nullptr, obuf,
                                              0, 2048, 2048, off, 2048ll*2048, 2048,
                                              nullptr, nullptr, nullptr, nullptr);
  gemmT<1><<<dim3(2,8,16), blk5, 0, stream>>>(obuf, wT_out, b_out, nullptr, eobuf,
                                              0, 512, 2048, off, 512ll*2048, 512,
                                              nullptr, nullptr, nullptr, nullptr);
  combine_k<<<2048, blk, 0, stream>>>(x2f, eobuf, gates, slot, off, (float*)d_out);
}

// Round 12
// 1031.471 us; speedup vs baseline: 1.0833x; 1.0607x over previous
//
#include <hip/hip_runtime.h>
#include <stdint.h>

#define DEVI __device__ __forceinline__
#define FENCE() asm volatile("" ::: "memory")
#define BAR() do{ FENCE(); __builtin_amdgcn_s_barrier(); FENCE(); }while(0)

typedef short short8 __attribute__((ext_vector_type(8)));
typedef short short4v __attribute__((ext_vector_type(4)));
typedef float f32x4 __attribute__((ext_vector_type(4)));

DEVI float bf2f(unsigned short s){ union{unsigned u; float f;} x; x.u = ((unsigned)s)<<16; return x.f; }
DEVI unsigned short f2bf(float f){ union{float f; unsigned u;} x; x.f=f; unsigned r = x.u + 0x7fff + ((x.u>>16)&1); return (unsigned short)(r>>16); }

DEVI void gload_lds16(const void* g, void* l){
  __builtin_amdgcn_global_load_lds((const __attribute__((address_space(1))) unsigned int*)g,
                                   (__attribute__((address_space(3))) unsigned int*)l, 16, 0, 0);
}

// ---------------------------------------------------------------------------
// Merged weight-prep kernel, 4-tile blocks for 4x memory-level parallelism.
// Each block: 4 adjacent (in N) 32x32 tiles; each thread issues 4 independent
// float4 loads back-to-back (latency amortized), 1 sync, 4 transposed stores.
__global__ __launch_bounds__(256)
void prep_all(const float* __restrict__ caw, const float* __restrict__ cpw,
              const float* __restrict__ w_in, const float* __restrict__ w1,
              const float* __restrict__ w2, const float* __restrict__ w_out,
              unsigned short* __restrict__ wT_attn, unsigned short* __restrict__ wT_proj,
              unsigned short* __restrict__ wT_in, unsigned short* __restrict__ wT1p,
              unsigned short* __restrict__ wT_2, unsigned short* __restrict__ wT_out,
              const float* __restrict__ x, const float* __restrict__ gw,
              const float* __restrict__ bw, unsigned short* __restrict__ xn)
{
  __shared__ float tile[4][32][33];
  int bid = blockIdx.x;
  int t = threadIdx.x;
  int tr = t>>3, tc = (t&7)*4;

  const float* src = nullptr; unsigned short* dst = nullptr;
  int K=0, N=0, kb=0, nb0=0;
  bool isw1 = false;

  if (bid < 192){                    // attn W: K=512,N=1536, nx4=12, ny=16
    int xb4 = bid % 12, yb = bid / 12;
    src = caw; dst = wT_attn; K=512; N=1536; kb=yb*32; nb0=xb4*128;
  } else if ((bid -= 192) < 64){     // proj: 512x512, nx4=4, ny=16
    int xb4 = bid % 4, yb = bid / 4;
    src = cpw; dst = wT_proj; K=512; N=512; kb=yb*32; nb0=xb4*128;
  } else if ((bid -= 64) < 4096){    // w_in: K=512,N=2048, nx4=16, ny=16, z=16
    int z = bid >> 8, r = bid & 255;
    int xb4 = r % 16, yb = r / 16;
    src = w_in + (size_t)z*512*2048; dst = wT_in + (size_t)z*2048*512;
    K=512; N=2048; kb=yb*32; nb0=xb4*128;
  } else if ((bid -= 4096) < 32768){ // w1 permuted: nx4=32, ny=64, z=16
    int z = bid >> 11, r = bid & 2047;
    int xb4 = r % 32, yb = r / 32;
    const float* s1 = w1 + (size_t)z*2048*4096;
    unsigned short* d1 = wT1p + (size_t)z*4096*2048;
    int k0 = yb*32;
    float4 v[4];
    #pragma unroll
    for (int j=0;j<4;j++){
      int g = xb4*4 + j;
      int srccol = (tc < 16) ? (g*16 + tc) : (2048 + g*16 + (tc-16));
      v[j] = *(const float4*)(s1 + (size_t)(k0+tr)*4096 + srccol);
    }
    #pragma unroll
    for (int j=0;j<4;j++){
      tile[j][tr][tc+0]=v[j].x; tile[j][tr][tc+1]=v[j].y;
      tile[j][tr][tc+2]=v[j].z; tile[j][tr][tc+3]=v[j].w;
    }
    __syncthreads();
    #pragma unroll
    for (int j=0;j<4;j++){
      int np0 = xb4*128 + 32*j;
      short4v ov;
      ov[0] = (short)f2bf(tile[j][tc+0][tr]);
      ov[1] = (short)f2bf(tile[j][tc+1][tr]);
      ov[2] = (short)f2bf(tile[j][tc+2][tr]);
      ov[3] = (short)f2bf(tile[j][tc+3][tr]);
      *(short4v*)(d1 + (size_t)(np0+tr)*2048 + k0 + tc) = ov;
    }
    return;
  } else if ((bid -= 32768) < 16384){ // w2: 2048x2048, nx4=16, ny=64, z=16
    int z = bid >> 10, r = bid & 1023;
    int xb4 = r % 16, yb = r / 16;
    src = w2 + (size_t)z*2048*2048; dst = wT_2 + (size_t)z*2048*2048;
    K=2048; N=2048; kb=yb*32; nb0=xb4*128;
  } else if ((bid -= 16384) < 4096){  // w_out: K=2048,N=512, nx4=4, ny=64, z=16
    int z = bid >> 8, r = bid & 255;
    int xb4 = r % 4, yb = r / 4;
    src = w_out + (size_t)z*2048*512; dst = wT_out + (size_t)z*512*2048;
    K=2048; N=512; kb=yb*32; nb0=xb4*128;
  } else {                            // rmsnorm: 512 blocks x 4 rows
    bid -= 4096;
    int row = bid*4 + (t>>6);
    int lane = t & 63;
    const float* xr = x + (size_t)row*512 + lane*8;
    float4 a = *(const float4*)xr;
    float4 c = *(const float4*)(xr+4);
    float ss = a.x*a.x+a.y*a.y+a.z*a.z+a.w*a.w + c.x*c.x+c.y*c.y+c.z*c.z+c.w*c.w;
    #pragma unroll
    for (int m=1;m<64;m<<=1) ss += __shfl_xor(ss, m);
    float inv = 1.0f / sqrtf(ss*(1.f/512.f) + 1e-6f);
    const float* gr = gw + lane*8; const float* br = bw + lane*8;
    float4 g0=*(const float4*)gr, g1=*(const float4*)(gr+4);
    float4 b0=*(const float4*)br, b1=*(const float4*)(br+4);
    short8 o;
    o[0]=(short)f2bf(a.x*inv*g0.x + b0.x);
    o[1]=(short)f2bf(a.y*inv*g0.y + b0.y);
    o[2]=(short)f2bf(a.z*inv*g0.z + b0.z);
    o[3]=(short)f2bf(a.w*inv*g0.w + b0.w);
    o[4]=(short)f2bf(c.x*inv*g1.x + b1.x);
    o[5]=(short)f2bf(c.y*inv*g1.y + b1.y);
    o[6]=(short)f2bf(c.z*inv*g1.z + b1.z);
    o[7]=(short)f2bf(c.w*inv*g1.w + b1.w);
    *(short8*)(xn + (size_t)row*512 + lane*8) = o;
    return;
  }
  // common 4-tile transpose path
  {
    float4 v[4];
    #pragma unroll
    for (int j=0;j<4;j++)
      v[j] = *(const float4*)(src + (size_t)(kb+tr)*N + nb0 + 32*j + tc);
    #pragma unroll
    for (int j=0;j<4;j++){
      tile[j][tr][tc+0]=v[j].x; tile[j][tr][tc+1]=v[j].y;
      tile[j][tr][tc+2]=v[j].z; tile[j][tr][tc+3]=v[j].w;
    }
    __syncthreads();
    #pragma unroll
    for (int j=0;j<4;j++){
      short4v ov;
      ov[0] = (short)f2bf(tile[j][tc+0][tr]);
      ov[1] = (short)f2bf(tile[j][tc+1][tr]);
      ov[2] = (short)f2bf(tile[j][tc+2][tr]);
      ov[3] = (short)f2bf(tile[j][tc+3][tr]);
      *(short4v*)(dst + (size_t)(nb0+32*j+tr)*K + kb + tc) = ov;
    }
  }
}

// ---------------------------------------------------------------------------
// 256x256 pipelined GEMM, 4 phases/K-tile (round-10 proven engine).
// EPI: 0 = fp32 out + bias; 1 = bf16 out + bias; 2 = fused SwiGLU (permuted
//      W1, N=4096 acc -> 2048-col bf16 out); 3 = fused qkv head-norm epilogue
#define READ_AFR(Q) do{ \
  _Pragma("unroll") \
  for (int m2=0;m2<2;m2++){ \
    int rt = wm*128 + ((Q)*2+m2)*16 + lrow; \
    _Pragma("unroll") \
    for (int kk=0;kk<2;kk++) \
      afr[m2][kk] = *(const short8*)(sA + rt*128 + (((lg+kk*4)^(rt&7))<<4)); \
  } \
}while(0)

#define QUADP(Q) do{ \
  __builtin_amdgcn_s_setprio(1); \
  _Pragma("unroll") \
  for (int m2=0;m2<2;m2++){ \
    _Pragma("unroll") \
    for (int n=0;n<4;n++){ \
      _Pragma("unroll") \
      for (int kk=0;kk<2;kk++) \
        acc[(Q)*2+m2][n] = __builtin_amdgcn_mfma_f32_16x16x32_bf16(afr[m2][kk], bfr[n][kk], acc[(Q)*2+m2][n], 0,0,0); \
    } \
  } \
  __builtin_amdgcn_s_setprio(0); \
}while(0)

template<int EPI>
__global__ __launch_bounds__(512, 2)
void gemmT(const unsigned short* __restrict__ A, const unsigned short* __restrict__ B,
           const float* __restrict__ bias,
           float* __restrict__ Cf, unsigned short* __restrict__ Ch,
           int M, int N, int K,
           const int* __restrict__ off, long long strideBz, long long strideBiasz,
           const float* __restrict__ alpha, unsigned short* __restrict__ oq,
           unsigned short* __restrict__ ok, unsigned short* __restrict__ ov)
{
  __shared__ char smem[131072];
  int z = blockIdx.z;
  int rowbase = 0, Mz = M;
  if (off){ rowbase = off[z]; Mz = off[z+1] - rowbase; }
  int row0 = blockIdx.y * 256;
  if (row0 >= Mz) return;
  int col0 = blockIdx.x * 256;
  const unsigned short* Ab = A + (size_t)(rowbase + row0) * K;
  const unsigned short* Bb = B + (size_t)z * strideBz + (size_t)col0 * K;
  const float* biasz = bias + (size_t)z * strideBiasz;

  int tid = threadIdx.x;
  int lane = tid & 63, w = tid >> 6;
  int lrow = lane & 15, lg = lane >> 4;
  int wm = w >> 2, wn = w & 3;

  f32x4 acc[8][4];
  #pragma unroll
  for (int i=0;i<8;i++){
    #pragma unroll
    for (int j=0;j<4;j++) acc[i][j] = f32x4{0.f,0.f,0.f,0.f};
  }
  int nkt = K >> 6;
  auto stage = [&](int kt2, int H){
    if (kt2 >= nkt) return;
    char* sl = smem + (kt2 & 1) * 65536 + H * 16384;
    int k0 = kt2 << 6;
    const unsigned short* src = (H < 2) ? Ab : Bb;
    int rbase = (H & 1) * 128;
    #pragma unroll
    for (int i=0;i<2;i++){
      int si = i*512 + tid;
      int r = si >> 3, kb = (si & 7) ^ (r & 7);
      gload_lds16(src + (size_t)(rbase + r)*K + k0 + kb*8, sl + si*16);
    }
  };
  stage(0,0); stage(0,1); stage(0,2); stage(0,3);
  stage(1,2); stage(1,3);
  asm volatile("s_waitcnt vmcnt(4)" ::: "memory");
  BAR();
  for (int kt = 0; kt < nkt; kt++){
    char* sA = smem + (kt & 1) * 65536;
    char* sB = sA + 32768;
    short8 bfr[4][2], afr[2][2];
    // ---- P0: all B-frags + A quad0; stage kt+1 A-lo + A-hi
    #pragma unroll
    for (int n=0;n<4;n++){
      int ct = wn*64 + n*16 + lrow;
      #pragma unroll
      for (int kk=0;kk<2;kk++)
        bfr[n][kk] = *(const short8*)(sB + ct*128 + (((lg+kk*4)^(ct&7))<<4));
    }
    READ_AFR(0);
    stage(kt+1, 0); stage(kt+1, 1);
    BAR();
    QUADP(0);
    BAR();
    // ---- P1: A quad1; stage B[kt+2]-lo
    READ_AFR(1);
    stage(kt+2, 2);
    BAR();
    QUADP(1);
    BAR();
    // ---- P2: A quad2; stage B[kt+2]-hi
    READ_AFR(2);
    stage(kt+2, 3);
    BAR();
    QUADP(2);
    BAR();
    // ---- P3: A quad3; counted vmcnt(4) -> A[kt+1],B[kt+1] landed
    READ_AFR(3);
    if (kt + 2 < nkt) { asm volatile("s_waitcnt vmcnt(4)" ::: "memory"); }
    else              { asm volatile("s_waitcnt vmcnt(0)" ::: "memory"); }
    BAR();
    QUADP(3);
    BAR();
  }
  if constexpr (EPI == 3){
    int tcol = col0 + wn*64;
    int type = tcol >> 9;           // 0=q, 1=k, 2=v
    int hd = (tcol >> 6) & 7;
    float al = alpha[hd];
    #pragma unroll
    for (int m=0;m<8;m++){
      #pragma unroll
      for (int j=0;j<4;j++){
        int row = row0 + wm*128 + m*16 + lg*4 + j;
        float v4[4]; float ss = 0.f;
        #pragma unroll
        for (int n=0;n<4;n++){
          int col = tcol + n*16 + lrow;
          v4[n] = acc[m][n][j] + biasz[col];
          ss += v4[n]*v4[n];
        }
        ss += __shfl_xor(ss,1); ss += __shfl_xor(ss,2);
        ss += __shfl_xor(ss,4); ss += __shfl_xor(ss,8);
        int b = row >> 10, tt = row & 1023;
        size_t hb = ((size_t)(b*8+hd))*65536;
        if (type == 0){
          float sc = al / (sqrtf(ss) + 1e-5f);
          #pragma unroll
          for (int n=0;n<4;n++)
            oq[hb + (size_t)tt*64 + n*16 + lrow] = f2bf(v4[n]*sc);
        } else if (type == 1){
          float sc = 1.f / (sqrtf(ss) + 1e-5f);
          #pragma unroll
          for (int n=0;n<4;n++)
            ok[hb + (size_t)tt*64 + n*16 + lrow] = f2bf(v4[n]*sc);
        } else {
          #pragma unroll
          for (int n=0;n<4;n++)
            ov[((size_t)(b*8+hd)*64 + n*16 + lrow)*1024 + tt] = f2bf(v4[n]);
        }
      }
    }
  } else {
    #pragma unroll
    for (int m=0;m<8;m++){
      #pragma unroll
      for (int j=0;j<4;j++){
        int row = row0 + wm*128 + m*16 + lg*4 + j;
        if (row < Mz){
          size_t rg = (size_t)(rowbase + row);
          if constexpr (EPI == 2){
            #pragma unroll
            for (int nf=0;nf<4;nf+=2){
              int pcol = col0 + wn*64 + nf*16;
              int scol = ((pcol>>5)<<4) + lrow;
              float av = acc[m][nf][j]   + biasz[scol];
              float gv = acc[m][nf+1][j] + biasz[2048 + scol];
              float sg = gv / (1.f + __expf(-gv));
              Ch[rg*2048 + scol] = f2bf(av * sg);
            }
          } else {
            #pragma unroll
            for (int n=0;n<4;n++){
              int col = col0 + wn*64 + n*16 + lrow;
              float v = acc[m][n][j] + biasz[col];
              size_t idx = rg * N + col;
              if constexpr (EPI == 0) Cf[idx] = v;
              else                    Ch[idx] = f2bf(v);
            }
          }
        }
      }
    }
  }
}

// ---------------------------------------------------------------------------
// Legacy 128x128 GEMM for the small proj matmul: +resid, fp32+bf16 out
__global__ __launch_bounds__(256)
void gemm_proj(const unsigned short* __restrict__ A, const unsigned short* __restrict__ B,
               const float* __restrict__ bias,
               float* __restrict__ Cf, unsigned short* __restrict__ Ch,
               const float* __restrict__ resid, int M, int N, int K)
{
  __shared__ char smem[32768];
  char* smA = smem; char* smB = smem + 16384;
  int row0 = blockIdx.y * 128;
  int col0 = blockIdx.x * 128;
  int t = threadIdx.x, w = t>>6, lane = t&63;
  int lrow = lane&15, lg = lane>>4;
  int wr = w>>1, wc = w&1;

  f32x4 acc[4][4];
  #pragma unroll
  for (int i=0;i<4;i++){
    #pragma unroll
    for (int j=0;j<4;j++) acc[i][j] = f32x4{0.f,0.f,0.f,0.f};
  }
  const size_t Abase = (size_t)row0 * K;
  const size_t Bbase = (size_t)col0 * K;
  int nkt = K >> 6;
  for (int kt=0; kt<nkt; kt++){
    __syncthreads();
    int k0 = kt*64;
    #pragma unroll
    for (int i=0;i<4;i++){
      int s = (i*4 + w)*64 + lane;
      int r = s>>3;
      int kb = (s&7) ^ (r&7);
      gload_lds16(A + Abase + (size_t)r*K + k0 + kb*8, smA + (size_t)(i*4+w)*1024);
      gload_lds16(B + Bbase + (size_t)r*K + k0 + kb*8, smB + (size_t)(i*4+w)*1024);
    }
    __syncthreads();
    #pragma unroll
    for (int ks=0; ks<2; ks++){
      short8 af[4], bf[4];
      int kbb = lg + ks*4;
      #pragma unroll
      for (int m=0;m<4;m++){
        int rt = wr*64 + m*16 + lrow;
        af[m] = *(const short8*)(smA + rt*128 + ((kbb ^ (rt&7))<<4));
      }
      #pragma unroll
      for (int n=0;n<4;n++){
        int rt = wc*64 + n*16 + lrow;
        bf[n] = *(const short8*)(smB + rt*128 + ((kbb ^ (rt&7))<<4));
      }
      #pragma unroll
      for (int m=0;m<4;m++){
        #pragma unroll
        for (int n=0;n<4;n++)
          acc[m][n] = __builtin_amdgcn_mfma_f32_16x16x32_bf16(af[m], bf[n], acc[m][n], 0,0,0);
      }
    }
  }
  #pragma unroll
  for (int m=0;m<4;m++){
    int rloc = wr*64 + m*16 + lg*4;
    #pragma unroll
    for (int j=0;j<4;j++){
      int row = row0 + rloc + j;
      size_t rg = (size_t)row;
      #pragma unroll
      for (int n=0;n<4;n++){
        int col = col0 + wc*64 + n*16 + lrow;
        float v = acc[m][n][j] + bias[col];
        size_t idx = rg * N + col;
        v += resid[idx];
        Cf[idx] = v;
        Ch[idx] = f2bf(v);
      }
    }
  }
}

// ---------------------------------------------------------------------------
// Flash attention, 64-row q-tiles (grid 16x16 = 256 blocks).
__global__ __launch_bounds__(256)
void attn_k(const unsigned short* __restrict__ q_s, const unsigned short* __restrict__ k_hat,
            const unsigned short* __restrict__ v_t, unsigned short* __restrict__ y)
{
  __shared__ char sm[51200];
  char* smK = sm + 18432;
  char* smV = sm + 34816;
  int qt = blockIdx.x, bh = blockIdx.y;
  int b = bh>>3, h = bh&7;
  int t = threadIdx.x, w = t>>6, lane = t&63;
  int lrow = lane&15, lg = lane>>4;
  int q0 = qt*64;
  const size_t hQK = (size_t)bh*1024*64;
  const size_t hV  = (size_t)bh*64*1024;

  #pragma unroll
  for (int i=0;i<2;i++){
    int si = i*256 + t;
    int r = si>>3, kb = (si&7)^(r&7);
    gload_lds16(q_s + hQK + (size_t)(q0+r)*64 + kb*8, sm + (size_t)si*16);
  }
  __syncthreads();
  short8 qf[2];
  #pragma unroll
  for (int ks=0;ks<2;ks++){
    int rt = w*16 + lrow;
    int kbb = lg + ks*4;
    qf[ks] = *(const short8*)(sm + rt*128 + ((kbb^(rt&7))<<4));
  }
  f32x4 oacc[4];
  #pragma unroll
  for (int j=0;j<4;j++) oacc[j] = f32x4{0.f,0.f,0.f,0.f};
  float mrun[4], lrun[4];
  #pragma unroll
  for (int j=0;j<4;j++){ mrun[j] = -1e30f; lrun[j] = 0.f; }
  char* Pw = sm + w*2304;

  int ktmax = (q0 + 63) >> 7;
  for (int kt=0; kt<=ktmax; kt++){
    __syncthreads();
    int t0 = kt*128;
    #pragma unroll
    for (int i=0;i<4;i++){
      int s = (i*4+w)*64 + lane;
      int r = s>>3, kb = (s&7)^(r&7);
      gload_lds16(k_hat + hQK + (size_t)(t0+r)*64 + kb*8, smK + (size_t)(i*4+w)*1024);
    }
    #pragma unroll
    for (int i=0;i<4;i++){
      int s = (i*4+w)*64 + lane;
      int d = s>>4, kb2 = s&15;
      int kb = kb2 ^ (d&7);
      gload_lds16(v_t + hV + (size_t)d*1024 + t0 + kb*8, smV + (size_t)(i*4+w)*1024);
    }
    __syncthreads();

    f32x4 sacc[8];
    #pragma unroll
    for (int j=0;j<8;j++) sacc[j] = f32x4{0.f,0.f,0.f,0.f};
    #pragma unroll
    for (int ks=0;ks<2;ks++){
      short8 kf[8];
      int kbb = lg + ks*4;
      #pragma unroll
      for (int nf=0;nf<8;nf++){
        int rt = nf*16+lrow;
        kf[nf] = *(const short8*)(smK + rt*128 + ((kbb^(rt&7))<<4));
      }
      #pragma unroll
      for (int nf=0;nf<8;nf++)
        sacc[nf] = __builtin_amdgcn_mfma_f32_16x16x32_bf16(qf[ks], kf[nf], sacc[nf], 0,0,0);
    }
    if (kt == ktmax){
      #pragma unroll
      for (int nf=0;nf<8;nf++){
        #pragma unroll
        for (int j=0;j<4;j++){
          int qi = q0 + w*16 + lg*4 + j;
          int ki = t0 + nf*16 + lrow;
          if (ki > qi) sacc[nf][j] = -1e30f;
        }
      }
    }
    #pragma unroll
    for (int j=0;j<4;j++){
      float mx = sacc[0][j];
      #pragma unroll
      for (int nf=1;nf<8;nf++) mx = fmaxf(mx, sacc[nf][j]);
      #pragma unroll
      for (int m=1;m<16;m<<=1) mx = fmaxf(mx, __shfl_xor(mx, m));
      float mnew = fmaxf(mrun[j], mx);
      float sc = __expf(mrun[j] - mnew);
      float rs = 0.f;
      #pragma unroll
      for (int nf=0;nf<8;nf++){
        float p = __expf(sacc[nf][j] - mnew);
        sacc[nf][j] = p; rs += p;
      }
      #pragma unroll
      for (int m=1;m<16;m<<=1) rs += __shfl_xor(rs, m);
      lrun[j] = lrun[j]*sc + rs;
      mrun[j] = mnew;
      #pragma unroll
      for (int n2=0;n2<4;n2++) oacc[n2][j] *= sc;
    }
    #pragma unroll
    for (int half=0; half<2; half++){
      #pragma unroll
      for (int nfh=0;nfh<4;nfh++){
        int nf = half*4 + nfh;
        #pragma unroll
        for (int j=0;j<4;j++){
          int row = lg*4 + j;
          int col = nfh*16 + lrow;
          *(unsigned short*)(Pw + (row*72 + col)*2) = f2bf(sacc[nf][j]);
        }
      }
      #pragma unroll
      for (int k2=0;k2<2;k2++){
        int ks2 = half*2 + k2;
        short8 pf, vf[4];
        pf = *(const short8*)(Pw + lrow*144 + lg*16 + k2*64);
        #pragma unroll
        for (int n2=0;n2<4;n2++){
          int d = n2*16+lrow;
          int kbb2 = lg + ks2*4;
          vf[n2] = *(const short8*)(smV + d*256 + ((kbb2^(d&7))<<4));
        }
        #pragma unroll
        for (int n2=0;n2<4;n2++)
          oacc[n2] = __builtin_amdgcn_mfma_f32_16x16x32_bf16(pf, vf[n2], oacc[n2], 0,0,0);
      }
    }
  }
  #pragma unroll
  for (int n2=0;n2<4;n2++){
    #pragma unroll
    for (int j=0;j<4;j++){
      float v = oacc[n2][j] / lrun[j];
      int qi = q0 + w*16 + lg*4 + j;
      int d = n2*16 + lrow;
      y[((size_t)(b*1024+qi))*512 + h*64 + d] = f2bf(v);
    }
  }
}

// ---------------------------------------------------------------------------
__global__ __launch_bounds__(256)
void router_topk(const float* __restrict__ x2f, const float* __restrict__ rw,
                 const float* __restrict__ rb, float* __restrict__ gates)
{
  int tkn = blockIdx.x*4 + (threadIdx.x>>6);
  int lane = threadIdx.x & 63;
  int e = lane & 15, p = lane >> 4;
  const float* xr = x2f + (size_t)tkn*512;
  float part = 0.f;
  for (int d = p*128; d < p*128+128; d++)
    part += xr[d] * rw[d*16 + e];
  part += __shfl_xor(part, 16);
  part += __shfl_xor(part, 32);
  float logit = part + rb[e];
  float mx = logit;
  #pragma unroll
  for (int m=1;m<16;m<<=1) mx = fmaxf(mx, __shfl_xor(mx, m));
  float ex = __expf(logit - mx);
  float sm = ex;
  #pragma unroll
  for (int m=1;m<16;m<<=1) sm += __shfl_xor(sm, m);
  float prob = ex / sm;
  bool taken = false;
  float ssum = 0.f;
  #pragma unroll
  for (int r=0;r<8;r++){
    float cv = taken ? -1.f : prob;
    int ci = e;
    #pragma unroll
    for (int m=1;m<16;m<<=1){
      float ov = __shfl_xor(cv, m);
      int oi = __shfl_xor(ci, m);
      if (ov > cv || (ov == cv && oi < ci)){ cv = ov; ci = oi; }
    }
    if (e == ci) taken = true;
    ssum += cv;
  }
  if (lane < 16)
    gates[(size_t)tkn*16 + e] = taken ? prob / ssum : 0.f;
}

// ---------------------------------------------------------------------------
__global__ void listbuild(const float* __restrict__ gates, int* __restrict__ list,
                          int* __restrict__ slot, int* __restrict__ cnt)
{
  int e = blockIdx.x;
  int tid = threadIdx.x, w = tid>>6, lane = tid&63;
  __shared__ int sbase;
  __shared__ int wsum[4];
  if (tid==0) sbase = 0;
  __syncthreads();
  for (int c=0;c<8;c++){
    int tk = c*256 + tid;
    bool flag = gates[(size_t)tk*16 + e] > 0.f;
    unsigned long long bal = __ballot(flag);
    if (lane==0) wsum[w] = (int)__popcll(bal);
    __syncthreads();
    int wpref = 0;
    for (int i=0;i<w;i++) wpref += wsum[i];
    int tot = wsum[0]+wsum[1]+wsum[2]+wsum[3];
    int lpref = (int)__popcll(bal & ((1ull<<lane)-1ull));
    if (flag){
      int pos = sbase + wpref + lpref;
      list[e*2048 + pos] = tk;
      slot[(size_t)tk*16 + e] = pos;
    }
    __syncthreads();
    if (tid==0) sbase += tot;
    __syncthreads();
  }
  if (tid==0) cnt[e] = sbase;
}

__global__ void prefix_off(const int* __restrict__ cnt, int* __restrict__ off){
  if (threadIdx.x==0 && blockIdx.x==0){
    int a=0;
    for (int e=0;e<16;e++){ off[e]=a; a+=cnt[e]; }
    off[16]=a;
  }
}

__global__ __launch_bounds__(256)
void gather_rows(const unsigned short* __restrict__ x2h, const int* __restrict__ list,
                 const int* __restrict__ cnt, const int* __restrict__ off,
                 unsigned short* __restrict__ xe)
{
  int e = blockIdx.y;
  int s = blockIdx.x*4 + (threadIdx.x>>6);
  if (s >= cnt[e]) return;
  int lane = threadIdx.x & 63;
  int tk = list[e*2048 + s];
  *(short8*)(xe + ((size_t)(off[e]+s))*512 + lane*8) =
      *(const short8*)(x2h + (size_t)tk*512 + lane*8);
}

__global__ __launch_bounds__(256)
void combine_k(const float* __restrict__ x2f, const unsigned short* __restrict__ eo,
               const float* __restrict__ gates, const int* __restrict__ slot,
               const int* __restrict__ off, float* __restrict__ out)
{
  int tkn = blockIdx.x;
  __shared__ float gs[16];
  __shared__ int rws[16];
  int tid = threadIdx.x;
  if (tid < 16){
    float g = gates[(size_t)tkn*16 + tid];
    gs[tid] = g;
    rws[tid] = (g > 0.f) ? (off[tid] + slot[(size_t)tkn*16 + tid]) : 0;
  }
  __syncthreads();
  for (int d = tid; d < 512; d += 256){
    float v = x2f[(size_t)tkn*512 + d];
    #pragma unroll
    for (int e=0;e<16;e++){
      float g = gs[e];
      if (g > 0.f) v += g * bf2f(eo[(size_t)rws[e]*512 + d]);
    }
    out[(size_t)tkn*512 + d] = v;
  }
}

// ---------------------------------------------------------------------------
extern "C" void kernel_launch(void* const* d_in, const int* in_sizes, int n_in,
                              void* d_out, int out_size, void* d_ws, size_t ws_size,
                              hipStream_t stream) {
  (void)in_sizes; (void)n_in; (void)out_size; (void)ws_size;
  const float* x    = (const float*)d_in[0];
  const float* gw   = (const float*)d_in[1];
  const float* bw   = (const float*)d_in[2];
  const float* caw  = (const float*)d_in[3];
  const float* cab  = (const float*)d_in[4];
  const float* alpha= (const float*)d_in[5];
  const float* cpw  = (const float*)d_in[6];
  const float* cpb  = (const float*)d_in[7];
  const float* rw   = (const float*)d_in[8];
  const float* rb   = (const float*)d_in[9];
  const float* w_in = (const float*)d_in[10];
  const float* b_in = (const float*)d_in[11];
  const float* w1   = (const float*)d_in[12];
  const float* b1   = (const float*)d_in[13];
  const float* w2   = (const float*)d_in[14];
  const float* b2   = (const float*)d_in[15];
  const float* w_out= (const float*)d_in[16];
  const float* b_out= (const float*)d_in[17];

  char* ws = (char*)d_ws;
  size_t o = 0;
  auto alloc = [&](size_t bytes)->char*{
    char* p = ws + o;
    o += (bytes + 255) & ~(size_t)255;
    return p;
  };
  const size_t PADROWS = 16896;  // 16384 + 256-tile overread pad
  unsigned short* wT_attn = (unsigned short*)alloc(1536ull*512*2);
  unsigned short* wT_proj = (unsigned short*)alloc(512ull*512*2);
  unsigned short* wT_in   = (unsigned short*)alloc(16ull*2048*512*2);
  unsigned short* wT1p    = (unsigned short*)alloc(16ull*4096*2048*2);
  unsigned short* wT_2    = (unsigned short*)alloc(16ull*2048*2048*2);
  unsigned short* wT_out  = (unsigned short*)alloc(16ull*512*2048*2);
  unsigned short* xn      = (unsigned short*)alloc(2048ull*512*2);
  unsigned short* q_s     = (unsigned short*)alloc(2048ull*512*2);
  unsigned short* k_hat   = (unsigned short*)alloc(2048ull*512*2);
  unsigned short* v_t     = (unsigned short*)alloc(2048ull*512*2);
  unsigned short* ybuf    = (unsigned short*)alloc(2048ull*512*2);
  float*          x2f     = (float*)alloc(2048ull*512*4);
  unsigned short* x2h     = (unsigned short*)alloc(2048ull*512*2);
  float*          gates   = (float*)alloc(2048ull*16*4);
  int*            slot    = (int*)alloc(2048ull*16*4);
  int*            list    = (int*)alloc(16ull*2048*4);
  int*            cnt     = (int*)alloc(64);
  int*            off     = (int*)alloc(256);
  unsigned short* xe      = (unsigned short*)alloc(PADROWS*512*2);   // + eo alias
  unsigned short* hbuf    = (unsigned short*)alloc(PADROWS*2048*2);  // + o alias
  unsigned short* sbuf    = (unsigned short*)alloc(PADROWS*2048*2);
  unsigned short* eobuf   = xe;   // xe dead after h-GEMM
  unsigned short* obuf    = hbuf; // hbuf dead after fused SwiGLU GEMM

  dim3 blk(256);
  dim3 blk5(512);
  // one merged prep dispatch (4-tile blocks): weight transposes + rmsnorm
  prep_all<<<58112, blk, 0, stream>>>(caw, cpw, w_in, w1, w2, w_out,
                                      wT_attn, wT_proj, wT_in, wT1p, wT_2, wT_out,
                                      x, gw, bw, xn);

  // qkv GEMM with fused head-norm epilogue (writes q_s/k_hat/v_t directly)
  gemmT<3><<<dim3(6, 8, 1), blk5, 0, stream>>>(xn, wT_attn, cab, nullptr, nullptr,
                                               2048, 1536, 512, nullptr, 0, 0,
                                               alpha, q_s, k_hat, v_t);
  attn_k<<<dim3(16,16), blk, 0, stream>>>(q_s, k_hat, v_t, ybuf);
  gemm_proj<<<dim3(4,16,1), blk, 0, stream>>>(ybuf, wT_proj, cpb, x2f, x2h, x, 2048, 512, 512);
  router_topk<<<512, blk, 0, stream>>>(x2f, rw, rb, gates);
  listbuild<<<16, blk, 0, stream>>>(gates, list, slot, cnt);
  prefix_off<<<1, 64, 0, stream>>>(cnt, off);
  gather_rows<<<dim3(512,16), blk, 0, stream>>>(x2h, list, cnt, off, xe);

  // experts (batched over z = expert, rows compacted via off[])
  gemmT<1><<<dim3(8,8,16), blk5, 0, stream>>>(xe, wT_in, b_in, nullptr, hbuf,
                                              0, 2048, 512, off, 2048ll*512, 2048,
                                              nullptr, nullptr, nullptr, nullptr);
  gemmT<2><<<dim3(16,8,16), blk5, 0, stream>>>(hbuf, wT1p, b1, nullptr, sbuf,
                                               0, 4096, 2048, off, 4096ll*2048, 4096,
                                               nullptr, nullptr, nullptr, nullptr);
  gemmT<1><<<dim3(8,8,16), blk5, 0, stream>>>(sbuf, wT_2, b2, nullptr, obuf,
                                              0, 2048, 2048, off, 2048ll*2048, 2048,
                                              nullptr, nullptr, nullptr, nullptr);
  gemmT<1><<<dim3(2,8,16), blk5, 0, stream>>>(obuf, wT_out, b_out, nullptr, eobuf,
                                              0, 512, 2048, off, 512ll*2048, 512,
                                              nullptr, nullptr, nullptr, nullptr);
  combine_k<<<2048, blk, 0, stream>>>(x2f, eobuf, gates, slot, off, (float*)d_out);
}

// Round 13
// 1002.206 us; speedup vs baseline: 1.1149x; 1.0292x over previous
//
#include <hip/hip_runtime.h>
#include <stdint.h>

#define DEVI __device__ __forceinline__
#define FENCE() asm volatile("" ::: "memory")
#define BAR() do{ FENCE(); __builtin_amdgcn_s_barrier(); FENCE(); }while(0)

typedef short short8 __attribute__((ext_vector_type(8)));
typedef short short4v __attribute__((ext_vector_type(4)));
typedef float f32x4 __attribute__((ext_vector_type(4)));

DEVI float bf2f(unsigned short s){ union{unsigned u; float f;} x; x.u = ((unsigned)s)<<16; return x.f; }
DEVI unsigned short f2bf(float f){ union{float f; unsigned u;} x; x.f=f; unsigned r = x.u + 0x7fff + ((x.u>>16)&1); return (unsigned short)(r>>16); }

DEVI void gload_lds16(const void* g, void* l){
  __builtin_amdgcn_global_load_lds((const __attribute__((address_space(1))) unsigned int*)g,
                                   (__attribute__((address_space(3))) unsigned int*)l, 16, 0, 0);
}

// ---------------------------------------------------------------------------
// Merged weight-prep kernel, 8-tile blocks for 8x memory-level parallelism.
// Each block: 8 adjacent (in N) 32x32 tiles; each thread issues 8 independent
// float4 loads back-to-back (HBM latency amortized), 1 sync, 8 stores.
__global__ __launch_bounds__(256)
void prep_all(const float* __restrict__ caw, const float* __restrict__ cpw,
              const float* __restrict__ w_in, const float* __restrict__ w1,
              const float* __restrict__ w2, const float* __restrict__ w_out,
              unsigned short* __restrict__ wT_attn, unsigned short* __restrict__ wT_proj,
              unsigned short* __restrict__ wT_in, unsigned short* __restrict__ wT1p,
              unsigned short* __restrict__ wT_2, unsigned short* __restrict__ wT_out,
              const float* __restrict__ x, const float* __restrict__ gw,
              const float* __restrict__ bw, unsigned short* __restrict__ xn)
{
  __shared__ float tile[8][32][33];
  int bid = blockIdx.x;
  int t = threadIdx.x;
  int tr = t>>3, tc = (t&7)*4;

  const float* src = nullptr; unsigned short* dst = nullptr;
  int K=0, N=0, kb=0, nb0=0;

  if (bid < 96){                     // attn W: K=512,N=1536, nx8=6, ny=16
    int xb8 = bid % 6, yb = bid / 6;
    src = caw; dst = wT_attn; K=512; N=1536; kb=yb*32; nb0=xb8*256;
  } else if ((bid -= 96) < 32){      // proj: 512x512, nx8=2, ny=16
    int xb8 = bid % 2, yb = bid / 2;
    src = cpw; dst = wT_proj; K=512; N=512; kb=yb*32; nb0=xb8*256;
  } else if ((bid -= 32) < 2048){    // w_in: K=512,N=2048, nx8=8, ny=16, z=16
    int z = bid >> 7, r = bid & 127;
    int xb8 = r % 8, yb = r / 8;
    src = w_in + (size_t)z*512*2048; dst = wT_in + (size_t)z*2048*512;
    K=512; N=2048; kb=yb*32; nb0=xb8*256;
  } else if ((bid -= 2048) < 16384){ // w1 permuted: nx8=16, ny=64, z=16
    int z = bid >> 10, r = bid & 1023;
    int xb8 = r % 16, yb = r / 16;
    const float* s1 = w1 + (size_t)z*2048*4096;
    unsigned short* d1 = wT1p + (size_t)z*4096*2048;
    int k0 = yb*32;
    float4 v[8];
    #pragma unroll
    for (int j=0;j<8;j++){
      int g = xb8*8 + j;
      int srccol = (tc < 16) ? (g*16 + tc) : (2048 + g*16 + (tc-16));
      v[j] = *(const float4*)(s1 + (size_t)(k0+tr)*4096 + srccol);
    }
    #pragma unroll
    for (int j=0;j<8;j++){
      tile[j][tr][tc+0]=v[j].x; tile[j][tr][tc+1]=v[j].y;
      tile[j][tr][tc+2]=v[j].z; tile[j][tr][tc+3]=v[j].w;
    }
    __syncthreads();
    #pragma unroll
    for (int j=0;j<8;j++){
      int np0 = xb8*256 + 32*j;
      short4v ov;
      ov[0] = (short)f2bf(tile[j][tc+0][tr]);
      ov[1] = (short)f2bf(tile[j][tc+1][tr]);
      ov[2] = (short)f2bf(tile[j][tc+2][tr]);
      ov[3] = (short)f2bf(tile[j][tc+3][tr]);
      *(short4v*)(d1 + (size_t)(np0+tr)*2048 + k0 + tc) = ov;
    }
    return;
  } else if ((bid -= 16384) < 8192){ // w2: 2048x2048, nx8=8, ny=64, z=16
    int z = bid >> 9, r = bid & 511;
    int xb8 = r % 8, yb = r / 8;
    src = w2 + (size_t)z*2048*2048; dst = wT_2 + (size_t)z*2048*2048;
    K=2048; N=2048; kb=yb*32; nb0=xb8*256;
  } else if ((bid -= 8192) < 2048){  // w_out: K=2048,N=512, nx8=2, ny=64, z=16
    int z = bid >> 7, r = bid & 127;
    int xb8 = r % 2, yb = r / 2;
    src = w_out + (size_t)z*2048*512; dst = wT_out + (size_t)z*512*2048;
    K=2048; N=512; kb=yb*32; nb0=xb8*256;
  } else {                           // rmsnorm: 512 blocks x 4 rows
    bid -= 2048;
    int row = bid*4 + (t>>6);
    int lane = t & 63;
    const float* xr = x + (size_t)row*512 + lane*8;
    float4 a = *(const float4*)xr;
    float4 c = *(const float4*)(xr+4);
    float ss = a.x*a.x+a.y*a.y+a.z*a.z+a.w*a.w + c.x*c.x+c.y*c.y+c.z*c.z+c.w*c.w;
    #pragma unroll
    for (int m=1;m<64;m<<=1) ss += __shfl_xor(ss, m);
    float inv = 1.0f / sqrtf(ss*(1.f/512.f) + 1e-6f);
    const float* gr = gw + lane*8; const float* br = bw + lane*8;
    float4 g0=*(const float4*)gr, g1=*(const float4*)(gr+4);
    float4 b0=*(const float4*)br, b1=*(const float4*)(br+4);
    short8 o;
    o[0]=(short)f2bf(a.x*inv*g0.x + b0.x);
    o[1]=(short)f2bf(a.y*inv*g0.y + b0.y);
    o[2]=(short)f2bf(a.z*inv*g0.z + b0.z);
    o[3]=(short)f2bf(a.w*inv*g0.w + b0.w);
    o[4]=(short)f2bf(c.x*inv*g1.x + b1.x);
    o[5]=(short)f2bf(c.y*inv*g1.y + b1.y);
    o[6]=(short)f2bf(c.z*inv*g1.z + b1.z);
    o[7]=(short)f2bf(c.w*inv*g1.w + b1.w);
    *(short8*)(xn + (size_t)row*512 + lane*8) = o;
    return;
  }
  // common 8-tile transpose path
  {
    float4 v[8];
    #pragma unroll
    for (int j=0;j<8;j++)
      v[j] = *(const float4*)(src + (size_t)(kb+tr)*N + nb0 + 32*j + tc);
    #pragma unroll
    for (int j=0;j<8;j++){
      tile[j][tr][tc+0]=v[j].x; tile[j][tr][tc+1]=v[j].y;
      tile[j][tr][tc+2]=v[j].z; tile[j][tr][tc+3]=v[j].w;
    }
    __syncthreads();
    #pragma unroll
    for (int j=0;j<8;j++){
      short4v ov;
      ov[0] = (short)f2bf(tile[j][tc+0][tr]);
      ov[1] = (short)f2bf(tile[j][tc+1][tr]);
      ov[2] = (short)f2bf(tile[j][tc+2][tr]);
      ov[3] = (short)f2bf(tile[j][tc+3][tr]);
      *(short4v*)(dst + (size_t)(nb0+32*j+tr)*K + kb + tc) = ov;
    }
  }
}

// ---------------------------------------------------------------------------
// 256x256 pipelined GEMM, 4 phases/K-tile (proven engine; experts only).
// EPI: 1 = bf16 out + bias; 2 = fused SwiGLU (permuted W1, N=4096 acc ->
//      2048-col bf16 out; bias[0..2047]=a, [2048..4095]=gate)
#define READ_AFR(Q) do{ \
  _Pragma("unroll") \
  for (int m2=0;m2<2;m2++){ \
    int rt = wm*128 + ((Q)*2+m2)*16 + lrow; \
    _Pragma("unroll") \
    for (int kk=0;kk<2;kk++) \
      afr[m2][kk] = *(const short8*)(sA + rt*128 + (((lg+kk*4)^(rt&7))<<4)); \
  } \
}while(0)

#define QUADP(Q) do{ \
  __builtin_amdgcn_s_setprio(1); \
  _Pragma("unroll") \
  for (int m2=0;m2<2;m2++){ \
    _Pragma("unroll") \
    for (int n=0;n<4;n++){ \
      _Pragma("unroll") \
      for (int kk=0;kk<2;kk++) \
        acc[(Q)*2+m2][n] = __builtin_amdgcn_mfma_f32_16x16x32_bf16(afr[m2][kk], bfr[n][kk], acc[(Q)*2+m2][n], 0,0,0); \
    } \
  } \
  __builtin_amdgcn_s_setprio(0); \
}while(0)

template<int EPI>
__global__ __launch_bounds__(512, 2)
void gemmT(const unsigned short* __restrict__ A, const unsigned short* __restrict__ B,
           const float* __restrict__ bias,
           unsigned short* __restrict__ Ch,
           int M, int N, int K,
           const int* __restrict__ off, long long strideBz, long long strideBiasz)
{
  __shared__ char smem[131072];
  int z = blockIdx.z;
  int rowbase = 0, Mz = M;
  if (off){ rowbase = off[z]; Mz = off[z+1] - rowbase; }
  int row0 = blockIdx.y * 256;
  if (row0 >= Mz) return;
  int col0 = blockIdx.x * 256;
  const unsigned short* Ab = A + (size_t)(rowbase + row0) * K;
  const unsigned short* Bb = B + (size_t)z * strideBz + (size_t)col0 * K;
  const float* biasz = bias + (size_t)z * strideBiasz;

  int tid = threadIdx.x;
  int lane = tid & 63, w = tid >> 6;
  int lrow = lane & 15, lg = lane >> 4;
  int wm = w >> 2, wn = w & 3;

  f32x4 acc[8][4];
  #pragma unroll
  for (int i=0;i<8;i++){
    #pragma unroll
    for (int j=0;j<4;j++) acc[i][j] = f32x4{0.f,0.f,0.f,0.f};
  }
  int nkt = K >> 6;
  auto stage = [&](int kt2, int H){
    if (kt2 >= nkt) return;
    char* sl = smem + (kt2 & 1) * 65536 + H * 16384;
    int k0 = kt2 << 6;
    const unsigned short* src = (H < 2) ? Ab : Bb;
    int rbase = (H & 1) * 128;
    #pragma unroll
    for (int i=0;i<2;i++){
      int si = i*512 + tid;
      int r = si >> 3, kb = (si & 7) ^ (r & 7);
      gload_lds16(src + (size_t)(rbase + r)*K + k0 + kb*8, sl + si*16);
    }
  };
  stage(0,0); stage(0,1); stage(0,2); stage(0,3);
  stage(1,2); stage(1,3);
  asm volatile("s_waitcnt vmcnt(4)" ::: "memory");
  BAR();
  for (int kt = 0; kt < nkt; kt++){
    char* sA = smem + (kt & 1) * 65536;
    char* sB = sA + 32768;
    short8 bfr[4][2], afr[2][2];
    #pragma unroll
    for (int n=0;n<4;n++){
      int ct = wn*64 + n*16 + lrow;
      #pragma unroll
      for (int kk=0;kk<2;kk++)
        bfr[n][kk] = *(const short8*)(sB + ct*128 + (((lg+kk*4)^(ct&7))<<4));
    }
    READ_AFR(0);
    stage(kt+1, 0); stage(kt+1, 1);
    BAR();
    QUADP(0);
    BAR();
    READ_AFR(1);
    stage(kt+2, 2);
    BAR();
    QUADP(1);
    BAR();
    READ_AFR(2);
    stage(kt+2, 3);
    BAR();
    QUADP(2);
    BAR();
    READ_AFR(3);
    if (kt + 2 < nkt) { asm volatile("s_waitcnt vmcnt(4)" ::: "memory"); }
    else              { asm volatile("s_waitcnt vmcnt(0)" ::: "memory"); }
    BAR();
    QUADP(3);
    BAR();
  }
  #pragma unroll
  for (int m=0;m<8;m++){
    #pragma unroll
    for (int j=0;j<4;j++){
      int row = row0 + wm*128 + m*16 + lg*4 + j;
      if (row < Mz){
        size_t rg = (size_t)(rowbase + row);
        if constexpr (EPI == 2){
          #pragma unroll
          for (int nf=0;nf<4;nf+=2){
            int pcol = col0 + wn*64 + nf*16;
            int scol = ((pcol>>5)<<4) + lrow;
            float av = acc[m][nf][j]   + biasz[scol];
            float gv = acc[m][nf+1][j] + biasz[2048 + scol];
            float sg = gv / (1.f + __expf(-gv));
            Ch[rg*2048 + scol] = f2bf(av * sg);
          }
        } else {
          #pragma unroll
          for (int n=0;n<4;n++){
            int col = col0 + wn*64 + n*16 + lrow;
            float v = acc[m][n][j] + biasz[col];
            Ch[rg * N + col] = f2bf(v);
          }
        }
      }
    }
  }
}

// ---------------------------------------------------------------------------
// 128x128 GEMM with fused qkv head-norm epilogue (EPI3 math validated in
// rounds 11-12; 192 blocks -> 75% GPU vs 48 at 256^2).
// Wave covers cols [col0 + wc*64, +64) = one head-section (128 | col0, so ok).
__global__ __launch_bounds__(256)
void gemm_qkv(const unsigned short* __restrict__ A, const unsigned short* __restrict__ B,
              const float* __restrict__ bias, const float* __restrict__ alpha,
              unsigned short* __restrict__ oq, unsigned short* __restrict__ ok,
              unsigned short* __restrict__ ov, int N, int K)
{
  __shared__ char smem[32768];
  char* smA = smem; char* smB = smem + 16384;
  int row0 = blockIdx.y * 128;
  int col0 = blockIdx.x * 128;
  int t = threadIdx.x, w = t>>6, lane = t&63;
  int lrow = lane&15, lg = lane>>4;
  int wr = w>>1, wc = w&1;

  f32x4 acc[4][4];
  #pragma unroll
  for (int i=0;i<4;i++){
    #pragma unroll
    for (int j=0;j<4;j++) acc[i][j] = f32x4{0.f,0.f,0.f,0.f};
  }
  const size_t Abase = (size_t)row0 * K;
  const size_t Bbase = (size_t)col0 * K;
  int nkt = K >> 6;
  for (int kt=0; kt<nkt; kt++){
    __syncthreads();
    int k0 = kt*64;
    #pragma unroll
    for (int i=0;i<4;i++){
      int s = (i*4 + w)*64 + lane;
      int r = s>>3;
      int kb = (s&7) ^ (r&7);
      gload_lds16(A + Abase + (size_t)r*K + k0 + kb*8, smA + (size_t)(i*4+w)*1024);
      gload_lds16(B + Bbase + (size_t)r*K + k0 + kb*8, smB + (size_t)(i*4+w)*1024);
    }
    __syncthreads();
    #pragma unroll
    for (int ks=0; ks<2; ks++){
      short8 af[4], bf[4];
      int kbb = lg + ks*4;
      #pragma unroll
      for (int m=0;m<4;m++){
        int rt = wr*64 + m*16 + lrow;
        af[m] = *(const short8*)(smA + rt*128 + ((kbb ^ (rt&7))<<4));
      }
      #pragma unroll
      for (int n=0;n<4;n++){
        int rt = wc*64 + n*16 + lrow;
        bf[n] = *(const short8*)(smB + rt*128 + ((kbb ^ (rt&7))<<4));
      }
      #pragma unroll
      for (int m=0;m<4;m++){
        #pragma unroll
        for (int n=0;n<4;n++)
          acc[m][n] = __builtin_amdgcn_mfma_f32_16x16x32_bf16(af[m], bf[n], acc[m][n], 0,0,0);
      }
    }
  }
  int tcol = col0 + wc*64;
  int type = tcol >> 9;           // 0=q, 1=k, 2=v
  int hd = (tcol >> 6) & 7;
  float al = alpha[hd];
  #pragma unroll
  for (int m=0;m<4;m++){
    #pragma unroll
    for (int j=0;j<4;j++){
      int row = row0 + wr*64 + m*16 + lg*4 + j;
      float v4[4]; float ss = 0.f;
      #pragma unroll
      for (int n=0;n<4;n++){
        v4[n] = acc[m][n][j] + bias[tcol + n*16 + lrow];
        ss += v4[n]*v4[n];
      }
      ss += __shfl_xor(ss,1); ss += __shfl_xor(ss,2);
      ss += __shfl_xor(ss,4); ss += __shfl_xor(ss,8);
      int b = row >> 10, tt = row & 1023;
      size_t hb = ((size_t)(b*8+hd))*65536;
      if (type == 0){
        float sc = al / (sqrtf(ss) + 1e-5f);
        #pragma unroll
        for (int n=0;n<4;n++)
          oq[hb + (size_t)tt*64 + n*16 + lrow] = f2bf(v4[n]*sc);
      } else if (type == 1){
        float sc = 1.f / (sqrtf(ss) + 1e-5f);
        #pragma unroll
        for (int n=0;n<4;n++)
          ok[hb + (size_t)tt*64 + n*16 + lrow] = f2bf(v4[n]*sc);
      } else {
        #pragma unroll
        for (int n=0;n<4;n++)
          ov[((size_t)(b*8+hd)*64 + n*16 + lrow)*1024 + tt] = f2bf(v4[n]);
      }
    }
  }
}

// ---------------------------------------------------------------------------
// Legacy 128x128 GEMM for the small proj matmul: +resid, fp32+bf16 out
__global__ __launch_bounds__(256)
void gemm_proj(const unsigned short* __restrict__ A, const unsigned short* __restrict__ B,
               const float* __restrict__ bias,
               float* __restrict__ Cf, unsigned short* __restrict__ Ch,
               const float* __restrict__ resid, int M, int N, int K)
{
  __shared__ char smem[32768];
  char* smA = smem; char* smB = smem + 16384;
  int row0 = blockIdx.y * 128;
  int col0 = blockIdx.x * 128;
  int t = threadIdx.x, w = t>>6, lane = t&63;
  int lrow = lane&15, lg = lane>>4;
  int wr = w>>1, wc = w&1;

  f32x4 acc[4][4];
  #pragma unroll
  for (int i=0;i<4;i++){
    #pragma unroll
    for (int j=0;j<4;j++) acc[i][j] = f32x4{0.f,0.f,0.f,0.f};
  }
  const size_t Abase = (size_t)row0 * K;
  const size_t Bbase = (size_t)col0 * K;
  int nkt = K >> 6;
  for (int kt=0; kt<nkt; kt++){
    __syncthreads();
    int k0 = kt*64;
    #pragma unroll
    for (int i=0;i<4;i++){
      int s = (i*4 + w)*64 + lane;
      int r = s>>3;
      int kb = (s&7) ^ (r&7);
      gload_lds16(A + Abase + (size_t)r*K + k0 + kb*8, smA + (size_t)(i*4+w)*1024);
      gload_lds16(B + Bbase + (size_t)r*K + k0 + kb*8, smB + (size_t)(i*4+w)*1024);
    }
    __syncthreads();
    #pragma unroll
    for (int ks=0; ks<2; ks++){
      short8 af[4], bf[4];
      int kbb = lg + ks*4;
      #pragma unroll
      for (int m=0;m<4;m++){
        int rt = wr*64 + m*16 + lrow;
        af[m] = *(const short8*)(smA + rt*128 + ((kbb ^ (rt&7))<<4));
      }
      #pragma unroll
      for (int n=0;n<4;n++){
        int rt = wc*64 + n*16 + lrow;
        bf[n] = *(const short8*)(smB + rt*128 + ((kbb ^ (rt&7))<<4));
      }
      #pragma unroll
      for (int m=0;m<4;m++){
        #pragma unroll
        for (int n=0;n<4;n++)
          acc[m][n] = __builtin_amdgcn_mfma_f32_16x16x32_bf16(af[m], bf[n], acc[m][n], 0,0,0);
      }
    }
  }
  #pragma unroll
  for (int m=0;m<4;m++){
    int rloc = wr*64 + m*16 + lg*4;
    #pragma unroll
    for (int j=0;j<4;j++){
      int row = row0 + rloc + j;
      size_t rg = (size_t)row;
      #pragma unroll
      for (int n=0;n<4;n++){
        int col = col0 + wc*64 + n*16 + lrow;
        float v = acc[m][n][j] + bias[col];
        size_t idx = rg * N + col;
        v += resid[idx];
        Cf[idx] = v;
        Ch[idx] = f2bf(v);
      }
    }
  }
}

// ---------------------------------------------------------------------------
// Flash attention, 64-row q-tiles (grid 16x16 = 256 blocks).
__global__ __launch_bounds__(256)
void attn_k(const unsigned short* __restrict__ q_s, const unsigned short* __restrict__ k_hat,
            const unsigned short* __restrict__ v_t, unsigned short* __restrict__ y)
{
  __shared__ char sm[51200];
  char* smK = sm + 18432;
  char* smV = sm + 34816;
  int qt = blockIdx.x, bh = blockIdx.y;
  int b = bh>>3, h = bh&7;
  int t = threadIdx.x, w = t>>6, lane = t&63;
  int lrow = lane&15, lg = lane>>4;
  int q0 = qt*64;
  const size_t hQK = (size_t)bh*1024*64;
  const size_t hV  = (size_t)bh*64*1024;

  #pragma unroll
  for (int i=0;i<2;i++){
    int si = i*256 + t;
    int r = si>>3, kb = (si&7)^(r&7);
    gload_lds16(q_s + hQK + (size_t)(q0+r)*64 + kb*8, sm + (size_t)si*16);
  }
  __syncthreads();
  short8 qf[2];
  #pragma unroll
  for (int ks=0;ks<2;ks++){
    int rt = w*16 + lrow;
    int kbb = lg + ks*4;
    qf[ks] = *(const short8*)(sm + rt*128 + ((kbb^(rt&7))<<4));
  }
  f32x4 oacc[4];
  #pragma unroll
  for (int j=0;j<4;j++) oacc[j] = f32x4{0.f,0.f,0.f,0.f};
  float mrun[4], lrun[4];
  #pragma unroll
  for (int j=0;j<4;j++){ mrun[j] = -1e30f; lrun[j] = 0.f; }
  char* Pw = sm + w*2304;

  int ktmax = (q0 + 63) >> 7;
  for (int kt=0; kt<=ktmax; kt++){
    __syncthreads();
    int t0 = kt*128;
    #pragma unroll
    for (int i=0;i<4;i++){
      int s = (i*4+w)*64 + lane;
      int r = s>>3, kb = (s&7)^(r&7);
      gload_lds16(k_hat + hQK + (size_t)(t0+r)*64 + kb*8, smK + (size_t)(i*4+w)*1024);
    }
    #pragma unroll
    for (int i=0;i<4;i++){
      int s = (i*4+w)*64 + lane;
      int d = s>>4, kb2 = s&15;
      int kb = kb2 ^ (d&7);
      gload_lds16(v_t + hV + (size_t)d*1024 + t0 + kb*8, smV + (size_t)(i*4+w)*1024);
    }
    __syncthreads();

    f32x4 sacc[8];
    #pragma unroll
    for (int j=0;j<8;j++) sacc[j] = f32x4{0.f,0.f,0.f,0.f};
    #pragma unroll
    for (int ks=0;ks<2;ks++){
      short8 kf[8];
      int kbb = lg + ks*4;
      #pragma unroll
      for (int nf=0;nf<8;nf++){
        int rt = nf*16+lrow;
        kf[nf] = *(const short8*)(smK + rt*128 + ((kbb^(rt&7))<<4));
      }
      #pragma unroll
      for (int nf=0;nf<8;nf++)
        sacc[nf] = __builtin_amdgcn_mfma_f32_16x16x32_bf16(qf[ks], kf[nf], sacc[nf], 0,0,0);
    }
    if (kt == ktmax){
      #pragma unroll
      for (int nf=0;nf<8;nf++){
        #pragma unroll
        for (int j=0;j<4;j++){
          int qi = q0 + w*16 + lg*4 + j;
          int ki = t0 + nf*16 + lrow;
          if (ki > qi) sacc[nf][j] = -1e30f;
        }
      }
    }
    #pragma unroll
    for (int j=0;j<4;j++){
      float mx = sacc[0][j];
      #pragma unroll
      for (int nf=1;nf<8;nf++) mx = fmaxf(mx, sacc[nf][j]);
      #pragma unroll
      for (int m=1;m<16;m<<=1) mx = fmaxf(mx, __shfl_xor(mx, m));
      float mnew = fmaxf(mrun[j], mx);
      float sc = __expf(mrun[j] - mnew);
      float rs = 0.f;
      #pragma unroll
      for (int nf=0;nf<8;nf++){
        float p = __expf(sacc[nf][j] - mnew);
        sacc[nf][j] = p; rs += p;
      }
      #pragma unroll
      for (int m=1;m<16;m<<=1) rs += __shfl_xor(rs, m);
      lrun[j] = lrun[j]*sc + rs;
      mrun[j] = mnew;
      #pragma unroll
      for (int n2=0;n2<4;n2++) oacc[n2][j] *= sc;
    }
    #pragma unroll
    for (int half=0; half<2; half++){
      #pragma unroll
      for (int nfh=0;nfh<4;nfh++){
        int nf = half*4 + nfh;
        #pragma unroll
        for (int j=0;j<4;j++){
          int row = lg*4 + j;
          int col = nfh*16 + lrow;
          *(unsigned short*)(Pw + (row*72 + col)*2) = f2bf(sacc[nf][j]);
        }
      }
      #pragma unroll
      for (int k2=0;k2<2;k2++){
        int ks2 = half*2 + k2;
        short8 pf, vf[4];
        pf = *(const short8*)(Pw + lrow*144 + lg*16 + k2*64);
        #pragma unroll
        for (int n2=0;n2<4;n2++){
          int d = n2*16+lrow;
          int kbb2 = lg + ks2*4;
          vf[n2] = *(const short8*)(smV + d*256 + ((kbb2^(d&7))<<4));
        }
        #pragma unroll
        for (int n2=0;n2<4;n2++)
          oacc[n2] = __builtin_amdgcn_mfma_f32_16x16x32_bf16(pf, vf[n2], oacc[n2], 0,0,0);
      }
    }
  }
  #pragma unroll
  for (int n2=0;n2<4;n2++){
    #pragma unroll
    for (int j=0;j<4;j++){
      float v = oacc[n2][j] / lrun[j];
      int qi = q0 + w*16 + lg*4 + j;
      int d = n2*16 + lrow;
      y[((size_t)(b*1024+qi))*512 + h*64 + d] = f2bf(v);
    }
  }
}

// ---------------------------------------------------------------------------
__global__ __launch_bounds__(256)
void router_topk(const float* __restrict__ x2f, const float* __restrict__ rw,
                 const float* __restrict__ rb, float* __restrict__ gates)
{
  int tkn = blockIdx.x*4 + (threadIdx.x>>6);
  int lane = threadIdx.x & 63;
  int e = lane & 15, p = lane >> 4;
  const float* xr = x2f + (size_t)tkn*512;
  float part = 0.f;
  for (int d = p*128; d < p*128+128; d++)
    part += xr[d] * rw[d*16 + e];
  part += __shfl_xor(part, 16);
  part += __shfl_xor(part, 32);
  float logit = part + rb[e];
  float mx = logit;
  #pragma unroll
  for (int m=1;m<16;m<<=1) mx = fmaxf(mx, __shfl_xor(mx, m));
  float ex = __expf(logit - mx);
  float sm = ex;
  #pragma unroll
  for (int m=1;m<16;m<<=1) sm += __shfl_xor(sm, m);
  float prob = ex / sm;
  bool taken = false;
  float ssum = 0.f;
  #pragma unroll
  for (int r=0;r<8;r++){
    float cv = taken ? -1.f : prob;
    int ci = e;
    #pragma unroll
    for (int m=1;m<16;m<<=1){
      float ov = __shfl_xor(cv, m);
      int oi = __shfl_xor(ci, m);
      if (ov > cv || (ov == cv && oi < ci)){ cv = ov; ci = oi; }
    }
    if (e == ci) taken = true;
    ssum += cv;
  }
  if (lane < 16)
    gates[(size_t)tkn*16 + e] = taken ? prob / ssum : 0.f;
}

// ---------------------------------------------------------------------------
__global__ void listbuild(const float* __restrict__ gates, int* __restrict__ list,
                          int* __restrict__ slot, int* __restrict__ cnt)
{
  int e = blockIdx.x;
  int tid = threadIdx.x, w = tid>>6, lane = tid&63;
  __shared__ int sbase;
  __shared__ int wsum[4];
  if (tid==0) sbase = 0;
  __syncthreads();
  for (int c=0;c<8;c++){
    int tk = c*256 + tid;
    bool flag = gates[(size_t)tk*16 + e] > 0.f;
    unsigned long long bal = __ballot(flag);
    if (lane==0) wsum[w] = (int)__popcll(bal);
    __syncthreads();
    int wpref = 0;
    for (int i=0;i<w;i++) wpref += wsum[i];
    int tot = wsum[0]+wsum[1]+wsum[2]+wsum[3];
    int lpref = (int)__popcll(bal & ((1ull<<lane)-1ull));
    if (flag){
      int pos = sbase + wpref + lpref;
      list[e*2048 + pos] = tk;
      slot[(size_t)tk*16 + e] = pos;
    }
    __syncthreads();
    if (tid==0) sbase += tot;
    __syncthreads();
  }
  if (tid==0) cnt[e] = sbase;
}

__global__ void prefix_off(const int* __restrict__ cnt, int* __restrict__ off){
  if (threadIdx.x==0 && blockIdx.x==0){
    int a=0;
    for (int e=0;e<16;e++){ off[e]=a; a+=cnt[e]; }
    off[16]=a;
  }
}

__global__ __launch_bounds__(256)
void gather_rows(const unsigned short* __restrict__ x2h, const int* __restrict__ list,
                 const int* __restrict__ cnt, const int* __restrict__ off,
                 unsigned short* __restrict__ xe)
{
  int e = blockIdx.y;
  int s = blockIdx.x*4 + (threadIdx.x>>6);
  if (s >= cnt[e]) return;
  int lane = threadIdx.x & 63;
  int tk = list[e*2048 + s];
  *(short8*)(xe + ((size_t)(off[e]+s))*512 + lane*8) =
      *(const short8*)(x2h + (size_t)tk*512 + lane*8);
}

__global__ __launch_bounds__(256)
void combine_k(const float* __restrict__ x2f, const unsigned short* __restrict__ eo,
               const float* __restrict__ gates, const int* __restrict__ slot,
               const int* __restrict__ off, float* __restrict__ out)
{
  int tkn = blockIdx.x;
  __shared__ float gs[16];
  __shared__ int rws[16];
  int tid = threadIdx.x;
  if (tid < 16){
    float g = gates[(size_t)tkn*16 + tid];
    gs[tid] = g;
    rws[tid] = (g > 0.f) ? (off[tid] + slot[(size_t)tkn*16 + tid]) : 0;
  }
  __syncthreads();
  for (int d = tid; d < 512; d += 256){
    float v = x2f[(size_t)tkn*512 + d];
    #pragma unroll
    for (int e=0;e<16;e++){
      float g = gs[e];
      if (g > 0.f) v += g * bf2f(eo[(size_t)rws[e]*512 + d]);
    }
    out[(size_t)tkn*512 + d] = v;
  }
}

// ---------------------------------------------------------------------------
extern "C" void kernel_launch(void* const* d_in, const int* in_sizes, int n_in,
                              void* d_out, int out_size, void* d_ws, size_t ws_size,
                              hipStream_t stream) {
  (void)in_sizes; (void)n_in; (void)out_size; (void)ws_size;
  const float* x    = (const float*)d_in[0];
  const float* gw   = (const float*)d_in[1];
  const float* bw   = (const float*)d_in[2];
  const float* caw  = (const float*)d_in[3];
  const float* cab  = (const float*)d_in[4];
  const float* alpha= (const float*)d_in[5];
  const float* cpw  = (const float*)d_in[6];
  const float* cpb  = (const float*)d_in[7];
  const float* rw   = (const float*)d_in[8];
  const float* rb   = (const float*)d_in[9];
  const float* w_in = (const float*)d_in[10];
  const float* b_in = (const float*)d_in[11];
  const float* w1   = (const float*)d_in[12];
  const float* b1   = (const float*)d_in[13];
  const float* w2   = (const float*)d_in[14];
  const float* b2   = (const float*)d_in[15];
  const float* w_out= (const float*)d_in[16];
  const float* b_out= (const float*)d_in[17];

  char* ws = (char*)d_ws;
  size_t o = 0;
  auto alloc = [&](size_t bytes)->char*{
    char* p = ws + o;
    o += (bytes + 255) & ~(size_t)255;
    return p;
  };
  const size_t PADROWS = 16896;  // 16384 + 256-tile overread pad
  unsigned short* wT_attn = (unsigned short*)alloc(1536ull*512*2);
  unsigned short* wT_proj = (unsigned short*)alloc(512ull*512*2);
  unsigned short* wT_in   = (unsigned short*)alloc(16ull*2048*512*2);
  unsigned short* wT1p    = (unsigned short*)alloc(16ull*4096*2048*2);
  unsigned short* wT_2    = (unsigned short*)alloc(16ull*2048*2048*2);
  unsigned short* wT_out  = (unsigned short*)alloc(16ull*512*2048*2);
  unsigned short* xn      = (unsigned short*)alloc(2048ull*512*2);
  unsigned short* q_s     = (unsigned short*)alloc(2048ull*512*2);
  unsigned short* k_hat   = (unsigned short*)alloc(2048ull*512*2);
  unsigned short* v_t     = (unsigned short*)alloc(2048ull*512*2);
  unsigned short* ybuf    = (unsigned short*)alloc(2048ull*512*2);
  float*          x2f     = (float*)alloc(2048ull*512*4);
  unsigned short* x2h     = (unsigned short*)alloc(2048ull*512*2);
  float*          gates   = (float*)alloc(2048ull*16*4);
  int*            slot    = (int*)alloc(2048ull*16*4);
  int*            list    = (int*)alloc(16ull*2048*4);
  int*            cnt     = (int*)alloc(64);
  int*            off     = (int*)alloc(256);
  unsigned short* xe      = (unsigned short*)alloc(PADROWS*512*2);   // + eo alias
  unsigned short* hbuf    = (unsigned short*)alloc(PADROWS*2048*2);  // + o alias
  unsigned short* sbuf    = (unsigned short*)alloc(PADROWS*2048*2);
  unsigned short* eobuf   = xe;   // xe dead after h-GEMM
  unsigned short* obuf    = hbuf; // hbuf dead after fused SwiGLU GEMM

  dim3 blk(256);
  dim3 blk5(512);
  // one merged prep dispatch (8-tile blocks): weight transposes + rmsnorm
  prep_all<<<29312, blk, 0, stream>>>(caw, cpw, w_in, w1, w2, w_out,
                                      wT_attn, wT_proj, wT_in, wT1p, wT_2, wT_out,
                                      x, gw, bw, xn);

  // qkv GEMM (128^2, 192 blocks) with fused head-norm epilogue
  gemm_qkv<<<dim3(12, 16), blk, 0, stream>>>(xn, wT_attn, cab, alpha,
                                             q_s, k_hat, v_t, 1536, 512);
  attn_k<<<dim3(16,16), blk, 0, stream>>>(q_s, k_hat, v_t, ybuf);
  gemm_proj<<<dim3(4,16,1), blk, 0, stream>>>(ybuf, wT_proj, cpb, x2f, x2h, x, 2048, 512, 512);
  router_topk<<<512, blk, 0, stream>>>(x2f, rw, rb, gates);
  listbuild<<<16, blk, 0, stream>>>(gates, list, slot, cnt);
  prefix_off<<<1, 64, 0, stream>>>(cnt, off);
  gather_rows<<<dim3(512,16), blk, 0, stream>>>(x2h, list, cnt, off, xe);

  // experts (batched over z = expert, rows compacted via off[])
  gemmT<1><<<dim3(8,8,16), blk5, 0, stream>>>(xe, wT_in, b_in, hbuf,
                                              0, 2048, 512, off, 2048ll*512, 2048);
  gemmT<2><<<dim3(16,8,16), blk5, 0, stream>>>(hbuf, wT1p, b1, sbuf,
                                               0, 4096, 2048, off, 4096ll*2048, 4096);
  gemmT<1><<<dim3(8,8,16), blk5, 0, stream>>>(sbuf, wT_2, b2, obuf,
                                              0, 2048, 2048, off, 2048ll*2048, 2048);
  gemmT<1><<<dim3(2,8,16), blk5, 0, stream>>>(obuf, wT_out, b_out, eobuf,
                                              0, 512, 2048, off, 512ll*2048, 512);
  combine_k<<<2048, blk, 0, stream>>>(x2f, eobuf, gates, slot, off, (float*)d_out);
}